// Round 13
// baseline (825.603 us; speedup 1.0000x reference)
//
#include <hip/hip_runtime.h>
#include <hip/hip_bf16.h>

// Qwen2VL vision block, MI355X gfx950.
// R13: gemmR LDS 48KB->32KB (2x16KB bufs) => 5 blocks/CU (occupancy lever,
//      m114 cross-block latency absorption). Depth-1 prefetch, entry
//      vmcnt(0)+barrier, stage(t+1) after barrier. Everything else = R12.

typedef __bf16 bf16_t;
typedef bf16_t bf16x8 __attribute__((ext_vector_type(8)));
typedef bf16_t bf16x4 __attribute__((ext_vector_type(4)));
typedef float f32x4 __attribute__((ext_vector_type(4)));

#define DIM 1280
#define NHEADS 16
#define HDIM 80
#define MLP 5120
#define NTOK 4096
#define QKV_N 3840

#define GLOAD_LDS16(gp, lp)                                                          \
    __builtin_amdgcn_global_load_lds((const __attribute__((address_space(1))) void*)(gp), \
                                     (__attribute__((address_space(3))) void*)(lp), 16, 0, 0)

// ---------------- fp32 -> bf16 conversion ----------------
__global__ void cvt_f32_bf16(const float* __restrict__ in, bf16_t* __restrict__ out, int n) {
    int i = (blockIdx.x * blockDim.x + threadIdx.x) * 4;
    int stride = gridDim.x * blockDim.x * 4;
    for (; i < n; i += stride) {
        float4 v = *(const float4*)(in + i);
        bf16x4 o;
        o[0] = (bf16_t)v.x; o[1] = (bf16_t)v.y; o[2] = (bf16_t)v.z; o[3] = (bf16_t)v.w;
        *(bf16x4*)(out + i) = o;
    }
}

// ---------------- LayerNorm (fp32 in, bf16 out) ----------------
__global__ __launch_bounds__(256) void ln_kernel(const float* __restrict__ x,
                                                 const float* __restrict__ w,
                                                 const float* __restrict__ b,
                                                 bf16_t* __restrict__ out) {
    int row = blockIdx.x;
    const float* xr = x + (long)row * DIM;
    float v[5];
    float s = 0.f, ss = 0.f;
#pragma unroll
    for (int j = 0; j < 5; j++) {
        v[j] = xr[j * 256 + threadIdx.x];
        s += v[j];
        ss += v[j] * v[j];
    }
#pragma unroll
    for (int off = 32; off > 0; off >>= 1) {
        s += __shfl_xor(s, off, 64);
        ss += __shfl_xor(ss, off, 64);
    }
    __shared__ float red[8];
    int wid = threadIdx.x >> 6;
    if ((threadIdx.x & 63) == 0) { red[wid] = s; red[wid + 4] = ss; }
    __syncthreads();
    s = red[0] + red[1] + red[2] + red[3];
    ss = red[4] + red[5] + red[6] + red[7];
    float mean = s * (1.f / DIM);
    float var = ss * (1.f / DIM) - mean * mean;
    float rstd = rsqrtf(var + 1e-6f);
    bf16_t* orow = out + (long)row * DIM;
#pragma unroll
    for (int j = 0; j < 5; j++) {
        int d = j * 256 + threadIdx.x;
        orow[d] = (bf16_t)((v[j] - mean) * rstd * w[d] + b[d]);
    }
}

// ---------------- prep: fused RoPE + layouts; Q pre-scaled by scale*log2e ----
__global__ __launch_bounds__(256) void prep_kernel(const bf16_t* __restrict__ qkv,
                                                   const float* __restrict__ rot,
                                                   bf16_t* __restrict__ Qd,
                                                   bf16_t* __restrict__ Kd,
                                                   bf16_t* __restrict__ Vt) {
    const float SCL = 0.11180339887498949f * 1.4426950408889634f;  // 1/sqrt(80)*log2(e)
    __shared__ bf16_t tv[64 * 88];
    const int tid = threadIdx.x;
    const int t0 = blockIdx.x * 64;
    const int h = blockIdx.y;

    for (int c = tid; c < 64 * 10; c += 256) {
        int tl = c / 10, a = c % 10;
        bf16x8 v = *(const bf16x8*)(qkv + (long)(t0 + tl) * QKV_N + 2 * DIM + h * HDIM + a * 8);
        *(bf16x8*)(tv + tl * 88 + a * 8) = v;
    }

    for (int c = tid; c < 64 * 10; c += 256) {
        int tl = c / 10, a = c % 10;
        long gq = (long)(t0 + tl) * QKV_N + h * HDIM + a * 4;
        bf16x4 q1 = *(const bf16x4*)(qkv + gq);
        bf16x4 q2 = *(const bf16x4*)(qkv + gq + 40);
        bf16x4 k1 = *(const bf16x4*)(qkv + gq + DIM);
        bf16x4 k2 = *(const bf16x4*)(qkv + gq + DIM + 40);
        float4 rv = *(const float4*)(rot + (long)(t0 + tl) * 40 + a * 4);
        float rr[4] = {rv.x, rv.y, rv.z, rv.w};
        bf16x4 oq1, oq2, ok1, ok2;
#pragma unroll
        for (int j = 0; j < 4; j++) {
            float c_, s_;
            __sincosf(rr[j], &s_, &c_);
            float x1 = (float)q1[j], x2 = (float)q2[j];
            oq1[j] = (bf16_t)((x1 * c_ - x2 * s_) * SCL);
            oq2[j] = (bf16_t)((x2 * c_ + x1 * s_) * SCL);
            x1 = (float)k1[j]; x2 = (float)k2[j];
            ok1[j] = (bf16_t)(x1 * c_ - x2 * s_);
            ok2[j] = (bf16_t)(x2 * c_ + x1 * s_);
        }
        long o = ((long)h * NTOK + t0 + tl) * 96 + a * 4;
        *(bf16x4*)(Qd + o) = oq1;
        *(bf16x4*)(Qd + o + 40) = oq2;
        *(bf16x4*)(Kd + o) = ok1;
        *(bf16x4*)(Kd + o + 40) = ok2;
    }
    {
        bf16x8 z;
#pragma unroll
        for (int j = 0; j < 8; j++) z[j] = (bf16_t)0.f;
        for (int c = tid; c < 64 * 2; c += 256) {
            int tl = c / 2, a = c % 2;
            long o = ((long)h * NTOK + t0 + tl) * 96 + 80 + a * 8;
            *(bf16x8*)(Qd + o) = z;
            *(bf16x8*)(Kd + o) = z;
        }
    }
    __syncthreads();

    for (int c = tid; c < 80 * 8; c += 256) {
        int d = c / 8, tc = c % 8;
        bf16x8 v;
#pragma unroll
        for (int j = 0; j < 8; j++) v[j] = tv[(tc * 8 + j) * 88 + d];
        *(bf16x8*)(Vt + ((long)h * HDIM + d) * NTOK + t0 + tc * 8) = v;
    }
}

// ---------------- reduce: out = res + bias + sum_z p_z ----------------
template <int NP>
__global__ void reduceN(const float* __restrict__ p, const float* __restrict__ b,
                        const float* __restrict__ res, float* __restrict__ out) {
    long i = (long)blockIdx.x * blockDim.x + threadIdx.x;  // float4 index
    float4 r = ((const float4*)res)[i];
    int c4 = (int)(i % (DIM / 4)) * 4;
    float4 bv = *(const float4*)(b + c4);
    float ax = r.x + bv.x, ay = r.y + bv.y, az = r.z + bv.z, aw = r.w + bv.w;
#pragma unroll
    for (int z = 0; z < NP; z++) {
        float4 a = ((const float4*)p)[i + (long)z * NTOK * DIM / 4];
        ax += a.x; ay += a.y; az += a.z; aw += a.w;
    }
    float4 o = {ax, ay, az, aw};
    ((float4*)out)[i] = o;
}

// ---------------- GEMM: C[M,N] = A[M,K] * B[N,K]^T (+epilogue) -----------------
// 128x128 tile, 4 waves (2M x 2N), BK=32. 2 LDS bufs x 16KB = 32KB -> 5 blocks/CU
// (occupancy-driven latency hiding, m114). Depth-1 prefetch: entry
// {vmcnt(0); s_barrier} (tile t's 4 loads are the only outstanding VMEM),
// then stage(t+1) into buf^1 (its readers finished in t-1, sealed by barrier),
// then 8 ds_read_b128 + 16 MFMA with compiler-managed lgkm waits.
// 64B rows; swizzle colb ^= (((row>>1)&3)<<4) both-sides (verified 0 conflicts).
// EPI 0: bf16=acc+bias | 1: f32=res+acc+bias | 2: bf16=qgelu(acc+bias) | 3: f32 partial
template <int EPI>
__global__ __launch_bounds__(256, 5) void gemmR(const bf16_t* __restrict__ A,
                                                const bf16_t* __restrict__ B,
                                                const float* __restrict__ bias,
                                                const float* __restrict__ res,
                                                void* __restrict__ Cv,
                                                int M, int N, int K, int kspl) {
    __shared__ char lds[2 * 16384];  // 32 KB
    const int tid = threadIdx.x;
    const int lane = tid & 63;
    const int l15 = lane & 15;
    const int g = lane >> 4;
    const int wid = tid >> 6;   // 0..3
    const int wr = wid >> 1;    // 0..1 (M)
    const int wc = wid & 1;     // 0..1 (N)

    // XCD-bijective block swizzle (x*y grid size % 8 == 0 for all launches)
    const int nx = gridDim.x;
    const int id = blockIdx.y * nx + blockIdx.x;
    const int cpx = (nx * gridDim.y) >> 3;
    const int sid = (id & 7) * cpx + (id >> 3);
    const int m0 = (sid / nx) * 128;
    const int n0 = (sid % nx) * 128;
    const int k0 = blockIdx.z * kspl;
    const int NT = kspl >> 5;  // K-tiles of 32

    // staging maps: per-lane global source pre-swizzled; LDS dest linear.
    const bf16_t *gA[2], *gB[2];
    int lAo[2], lBo[2];
#pragma unroll
    for (int j = 0; j < 2; j++) {
        int off = j * 4096 + tid * 16;                  // byte offset in 8KB region
        int row = off >> 6;                             // 0..127 (64B rows)
        int cb = (off & 63) ^ (((row >> 1) & 3) << 4);  // swizzled byte col
        gA[j] = A + (long)(m0 + row) * K + k0 + (cb >> 1);
        gB[j] = B + (long)(n0 + row) * K + k0 + (cb >> 1);
        lAo[j] = j * 4096 + wid * 1024;
        lBo[j] = 8192 + j * 4096 + wid * 1024;
    }

    f32x4 acc[4][4];
#pragma unroll
    for (int i = 0; i < 4; i++)
#pragma unroll
        for (int j = 0; j < 4; j++) acc[i][j] = (f32x4){0.f, 0.f, 0.f, 0.f};

    auto stage = [&](int buf, int t) {
        char* sb = lds + buf * 16384;
#pragma unroll
        for (int j = 0; j < 2; j++) GLOAD_LDS16(gA[j] + t * 32, sb + lAo[j]);
#pragma unroll
        for (int j = 0; j < 2; j++) GLOAD_LDS16(gB[j] + t * 32, sb + lBo[j]);
    };

    stage(0, 0);

    for (int t = 0; t < NT; ++t) {
        // tile t's 4 loads are the only outstanding VMEM; drain + publish.
        asm volatile("s_waitcnt vmcnt(0)\n\ts_barrier" ::: "memory");
        if (t + 1 < NT) stage((t + 1) & 1, t + 1);

        const char* pA = lds + (t & 1) * 16384;
        const char* pB = pA + 8192;
        bf16x8 af[4], bb[4];
#pragma unroll
        for (int m = 0; m < 4; m++) {
            int r = wr * 64 + m * 16 + l15;
            af[m] = *(const bf16x8*)(pA + r * 64 + ((g * 16) ^ (((r >> 1) & 3) << 4)));
        }
#pragma unroll
        for (int n = 0; n < 4; n++) {
            int r = wc * 64 + n * 16 + l15;
            bb[n] = *(const bf16x8*)(pB + r * 64 + ((g * 16) ^ (((r >> 1) & 3) << 4)));
        }
        __builtin_amdgcn_s_setprio(1);
#pragma unroll
        for (int m = 0; m < 4; m++)
#pragma unroll
            for (int n = 0; n < 4; n++)
                acc[m][n] = __builtin_amdgcn_mfma_f32_16x16x32_bf16(af[m], bb[n],
                                                                    acc[m][n], 0, 0, 0);
        __builtin_amdgcn_s_setprio(0);
    }

    // epilogue: D row = (lane>>4)*4 + rr, col = lane&15
#pragma unroll
    for (int m = 0; m < 4; m++)
#pragma unroll
        for (int n = 0; n < 4; n++) {
            const int col = n0 + wc * 64 + n * 16 + l15;
            const float bv = (EPI == 3) ? 0.f : bias[col];
#pragma unroll
            for (int rr = 0; rr < 4; rr++) {
                const int row = m0 + wr * 64 + m * 16 + g * 4 + rr;
                const long idx = (long)row * N + col;
                float val = acc[m][n][rr] + bv;
                if (EPI == 0) {
                    ((bf16_t*)Cv)[idx] = (bf16_t)val;
                } else if (EPI == 1) {
                    ((float*)Cv)[idx] = res[idx] + val;
                } else if (EPI == 2) {
                    float ge = val / (1.f + __expf(-1.702f * val));
                    ((bf16_t*)Cv)[idx] = (bf16_t)ge;
                } else {
                    ((float*)Cv)[(long)blockIdx.z * M * N + idx] = val;
                }
            }
        }
}

// ---------------- Flash attention v3: no-max softmax (unchanged from R12) ----
__global__ __launch_bounds__(256) void attn_kernel(const bf16_t* __restrict__ Qd,
                                                   const bf16_t* __restrict__ Kd,
                                                   const bf16_t* __restrict__ Vt,
                                                   const int* __restrict__ cu,
                                                   int ncu,
                                                   bf16_t* __restrict__ out) {
    __shared__ bf16_t lK[64 * 104];   // [k][d], stride 104
    __shared__ bf16_t lV[96 * 64];    // [d][k], 128B rows + XOR swizzle
    __shared__ bf16_t lP[4 * 16 * 72];

    const int tid = threadIdx.x;
    const int lane = tid & 63;
    const int l15 = lane & 15;
    const int g = lane >> 4;
    const int wid = tid >> 6;
    const int h = blockIdx.y;
    const int q0 = blockIdx.x * 64;

    int sseg = 0;
    for (int j = 1; j < ncu - 1; j++) if (q0 >= cu[j]) sseg = j;
    const int kbeg = cu[sseg], kend = cu[sseg + 1];

    bf16x8 aq[3];
    {
        const bf16_t* qp = Qd + ((long)h * NTOK + q0 + wid * 16 + l15) * 96;
#pragma unroll
        for (int ks = 0; ks < 3; ks++)
            aq[ks] = *(const bf16x8*)(qp + ks * 32 + g * 8);
    }

    for (int c = tid; c < 16 * 8; c += 256) {
        int d = 80 + c / 8, a = c % 8;
        bf16x8 v;
#pragma unroll
        for (int j = 0; j < 8; j++) v[j] = (d == 80) ? (bf16_t)1.f : (bf16_t)0.f;
        *(bf16x8*)((char*)lV + d * 128 + ((a * 16) ^ ((d & 7) << 4))) = v;
    }

    f32x4 o[6];
#pragma unroll
    for (int n = 0; n < 6; n++) o[n] = (f32x4){0.f, 0.f, 0.f, 0.f};

    bf16x8 rK[3], rV[3];
    auto ldK = [&](int kt) {
#pragma unroll
        for (int i = 0; i < 3; i++) {
            int c = tid + i * 256;
            int row = c / 12, c16 = c % 12;
            rK[i] = *(const bf16x8*)(Kd + ((long)h * NTOK + kt + row) * 96 + c16 * 8);
        }
    };
    auto ldV = [&](int kt) {
#pragma unroll
        for (int i = 0; i < 3; i++) {
            int c = tid + i * 256;
            if (c < 640) {
                int d = c / 8, a = c % 8;
                rV[i] = *(const bf16x8*)(Vt + ((long)h * HDIM + d) * NTOK + kt + a * 8);
            }
        }
    };
    auto wrKV = [&]() {
#pragma unroll
        for (int i = 0; i < 3; i++) {
            int c = tid + i * 256;
            int row = c / 12, c16 = c % 12;
            *(bf16x8*)(lK + row * 104 + c16 * 8) = rK[i];
        }
#pragma unroll
        for (int i = 0; i < 3; i++) {
            int c = tid + i * 256;
            if (c < 640) {
                int d = c / 8, a = c % 8;
                *(bf16x8*)((char*)lV + d * 128 + ((a * 16) ^ ((d & 7) << 4))) = rV[i];
            }
        }
    };

    ldK(kbeg); ldV(kbeg);
    wrKV();
    __syncthreads();

    for (int kt = kbeg; kt < kend; kt += 64) {
        const bool more = (kt + 64 < kend);
        if (more) { ldK(kt + 64); ldV(kt + 64); }

        f32x4 s[4];
#pragma unroll
        for (int n = 0; n < 4; n++) s[n] = (f32x4){0.f, 0.f, 0.f, 0.f};
#pragma unroll
        for (int n = 0; n < 4; n++)
#pragma unroll
            for (int ks = 0; ks < 3; ks++) {
                bf16x8 kf = *(const bf16x8*)(lK + (n * 16 + l15) * 104 + ks * 32 + g * 8);
                s[n] = __builtin_amdgcn_mfma_f32_16x16x32_bf16(aq[ks], kf, s[n], 0, 0, 0);
            }

#pragma unroll
        for (int n = 0; n < 4; n++)
#pragma unroll
            for (int r = 0; r < 4; r++)
                lP[wid * 1152 + (g * 4 + r) * 72 + n * 16 + l15] = (bf16_t)exp2f(s[n][r]);

        asm volatile("s_waitcnt lgkmcnt(0)" ::: "memory");
        bf16x8 pa[2];
#pragma unroll
        for (int ks = 0; ks < 2; ks++)
            pa[ks] = *(const bf16x8*)(lP + wid * 1152 + l15 * 72 + ks * 32 + g * 8);
#pragma unroll
        for (int n = 0; n < 6; n++)
#pragma unroll
            for (int ks = 0; ks < 2; ks++) {
                int rv = n * 16 + l15;
                bf16x8 vb = *(const bf16x8*)((char*)lV + rv * 128 +
                                             ((ks * 64 + g * 16) ^ ((rv & 7) << 4)));
                o[n] = __builtin_amdgcn_mfma_f32_16x16x32_bf16(pa[ks], vb, o[n], 0, 0, 0);
            }
        __syncthreads();
        if (more) wrKV();
        __syncthreads();
    }

    float lI[4];
#pragma unroll
    for (int r = 0; r < 4; r++) lI[r] = __shfl(o[5][r], lane & 48, 64);

#pragma unroll
    for (int n = 0; n < 5; n++)
#pragma unroll
        for (int r = 0; r < 4; r++) {
            int row = q0 + wid * 16 + g * 4 + r;
            out[(long)row * DIM + h * HDIM + n * 16 + l15] = (bf16_t)(o[n][r] / lI[r]);
        }
}

// ---------------- launch ----------------
extern "C" void kernel_launch(void* const* d_in, const int* in_sizes, int n_in,
                              void* d_out, int out_size, void* d_ws, size_t ws_size,
                              hipStream_t stream) {
    const float* hidden = (const float*)d_in[0];
    const float* rot    = (const float*)d_in[1];
    const int*   cu     = (const int*)d_in[2];
    const float* n1w    = (const float*)d_in[3];
    const float* n1b    = (const float*)d_in[4];
    const float* n2w    = (const float*)d_in[5];
    const float* n2b    = (const float*)d_in[6];
    const float* qkv_w  = (const float*)d_in[7];
    const float* qkv_b  = (const float*)d_in[8];
    const float* proj_w = (const float*)d_in[9];
    const float* proj_b = (const float*)d_in[10];
    const float* fc1_w  = (const float*)d_in[11];
    const float* fc1_b  = (const float*)d_in[12];
    const float* fc2_w  = (const float*)d_in[13];
    const float* fc2_b  = (const float*)d_in[14];
    float* outp = (float*)d_out;

    char* ws = (char*)d_ws;
    bf16_t* w2   = (bf16_t*)(ws);                  // [0,13.1M)        cvt->FC2
    bf16_t* w1   = (bf16_t*)(ws + 13107200);       // [13.1M,26.2M)    cvt->FC1
    bf16_t* wp   = (bf16_t*)(ws + 26214400);       // [26.2M,29.5M)    cvt->proj
    bf16_t* wq   = (bf16_t*)(ws + 29491200);       // [29.5M,39.3M)    cvt->QKV
    bf16_t* xln  = (bf16_t*)(ws + 39321600);       // [39.3M,49.8M)    LN1->QKV, LN2->FC1
    bf16_t* qkvb = (bf16_t*)(ws + 49807360);       // [49.8M,81.3M)    QKV->prep
    bf16_t* Qd   = (bf16_t*)(ws + 81264640);       // [81.3M,93.8M)    prep->attn
    bf16_t* Kd   = (bf16_t*)(ws + 93847552);       // [93.8M,106.4M)   prep->attn
    bf16_t* Vt   = (bf16_t*)(ws + 106430464);      // [106.4M,116.9M)  prep->attn
    bf16_t* attno= (bf16_t*)(ws + 116916224);      // [116.9M,127.4M)  attn->proj
    bf16_t* act  = (bf16_t*)(ws + 49807360);       // [49.8M,91.75M)   FC1->FC2 (qkvb/Qd dead)
    float*  p01  = (float*)(ws + 91750400);        // [91.75M,133.69M) FC2 partials x2
    // h (f32) lives in d_out: proj writes (EPI1), LN2 reads, FC2-reduce accumulates.

    int ncu = in_sizes[2];

    cvt_f32_bf16<<<2048, 256, 0, stream>>>(qkv_w, wq, QKV_N * DIM);
    cvt_f32_bf16<<<1024, 256, 0, stream>>>(proj_w, wp, DIM * DIM);
    cvt_f32_bf16<<<2048, 256, 0, stream>>>(fc1_w, w1, MLP * DIM);
    cvt_f32_bf16<<<2048, 256, 0, stream>>>(fc2_w, w2, DIM * MLP);

    ln_kernel<<<NTOK, 256, 0, stream>>>(hidden, n1w, n1b, xln);
    // QKV: 4096x3840x1280 -> 30x32 = 960 blocks, NT=40
    gemmR<0><<<dim3(QKV_N / 128, NTOK / 128, 1), 256, 0, stream>>>(
        xln, wq, qkv_b, nullptr, qkvb, NTOK, QKV_N, DIM, DIM);
    prep_kernel<<<dim3(NTOK / 64, NHEADS), 256, 0, stream>>>(qkvb, rot, Qd, Kd, Vt);
    attn_kernel<<<dim3(NTOK / 64, NHEADS), 256, 0, stream>>>(Qd, Kd, Vt, cu, ncu, attno);
    // proj: 4096x1280x1280 -> 10x32 = 320 blocks, NT=40, direct h = hidden+acc+bias
    gemmR<1><<<dim3(DIM / 128, NTOK / 128, 1), 256, 0, stream>>>(
        attno, wp, proj_b, hidden, outp, NTOK, DIM, DIM, DIM);
    ln_kernel<<<NTOK, 256, 0, stream>>>(outp, n2w, n2b, xln);
    // FC1: 40x32 = 1280 blocks, NT=40
    gemmR<2><<<dim3(MLP / 128, NTOK / 128, 1), 256, 0, stream>>>(
        xln, w1, fc1_b, nullptr, act, NTOK, MLP, DIM, DIM);
    // FC2: split-K x2 -> 10x32x2 = 640 blocks, NT=80
    gemmR<3><<<dim3(DIM / 128, NTOK / 128, 2), 256, 0, stream>>>(
        act, w2, nullptr, nullptr, p01, NTOK, DIM, MLP, 2560);
    reduceN<2><<<NTOK * DIM / 4 / 256, 256, 0, stream>>>(p01, fc2_b, outp, outp);
}

// Round 14
// 349.635 us; speedup vs baseline: 2.3613x; 2.3613x over previous
//
#include <hip/hip_runtime.h>
#include <hip/hip_bf16.h>

// Qwen2VL vision block, MI355X gfx950.
// R14: R13 with the launch_bounds spill fixed — __launch_bounds__(256,3)
//      (allocator budget ~170 VGPR, no spill; R13's (256,5) capped at ~102
//      and spilled acc -> 645MB scratch traffic). 32KB LDS still gives
//      5 blocks/CU at the natural 68-VGPR allocation.

typedef __bf16 bf16_t;
typedef bf16_t bf16x8 __attribute__((ext_vector_type(8)));
typedef bf16_t bf16x4 __attribute__((ext_vector_type(4)));
typedef float f32x4 __attribute__((ext_vector_type(4)));

#define DIM 1280
#define NHEADS 16
#define HDIM 80
#define MLP 5120
#define NTOK 4096
#define QKV_N 3840

#define GLOAD_LDS16(gp, lp)                                                          \
    __builtin_amdgcn_global_load_lds((const __attribute__((address_space(1))) void*)(gp), \
                                     (__attribute__((address_space(3))) void*)(lp), 16, 0, 0)

// ---------------- fp32 -> bf16 conversion ----------------
__global__ void cvt_f32_bf16(const float* __restrict__ in, bf16_t* __restrict__ out, int n) {
    int i = (blockIdx.x * blockDim.x + threadIdx.x) * 4;
    int stride = gridDim.x * blockDim.x * 4;
    for (; i < n; i += stride) {
        float4 v = *(const float4*)(in + i);
        bf16x4 o;
        o[0] = (bf16_t)v.x; o[1] = (bf16_t)v.y; o[2] = (bf16_t)v.z; o[3] = (bf16_t)v.w;
        *(bf16x4*)(out + i) = o;
    }
}

// ---------------- LayerNorm (fp32 in, bf16 out) ----------------
__global__ __launch_bounds__(256) void ln_kernel(const float* __restrict__ x,
                                                 const float* __restrict__ w,
                                                 const float* __restrict__ b,
                                                 bf16_t* __restrict__ out) {
    int row = blockIdx.x;
    const float* xr = x + (long)row * DIM;
    float v[5];
    float s = 0.f, ss = 0.f;
#pragma unroll
    for (int j = 0; j < 5; j++) {
        v[j] = xr[j * 256 + threadIdx.x];
        s += v[j];
        ss += v[j] * v[j];
    }
#pragma unroll
    for (int off = 32; off > 0; off >>= 1) {
        s += __shfl_xor(s, off, 64);
        ss += __shfl_xor(ss, off, 64);
    }
    __shared__ float red[8];
    int wid = threadIdx.x >> 6;
    if ((threadIdx.x & 63) == 0) { red[wid] = s; red[wid + 4] = ss; }
    __syncthreads();
    s = red[0] + red[1] + red[2] + red[3];
    ss = red[4] + red[5] + red[6] + red[7];
    float mean = s * (1.f / DIM);
    float var = ss * (1.f / DIM) - mean * mean;
    float rstd = rsqrtf(var + 1e-6f);
    bf16_t* orow = out + (long)row * DIM;
#pragma unroll
    for (int j = 0; j < 5; j++) {
        int d = j * 256 + threadIdx.x;
        orow[d] = (bf16_t)((v[j] - mean) * rstd * w[d] + b[d]);
    }
}

// ---------------- prep: fused RoPE + layouts; Q pre-scaled by scale*log2e ----
__global__ __launch_bounds__(256) void prep_kernel(const bf16_t* __restrict__ qkv,
                                                   const float* __restrict__ rot,
                                                   bf16_t* __restrict__ Qd,
                                                   bf16_t* __restrict__ Kd,
                                                   bf16_t* __restrict__ Vt) {
    const float SCL = 0.11180339887498949f * 1.4426950408889634f;  // 1/sqrt(80)*log2(e)
    __shared__ bf16_t tv[64 * 88];
    const int tid = threadIdx.x;
    const int t0 = blockIdx.x * 64;
    const int h = blockIdx.y;

    for (int c = tid; c < 64 * 10; c += 256) {
        int tl = c / 10, a = c % 10;
        bf16x8 v = *(const bf16x8*)(qkv + (long)(t0 + tl) * QKV_N + 2 * DIM + h * HDIM + a * 8);
        *(bf16x8*)(tv + tl * 88 + a * 8) = v;
    }

    for (int c = tid; c < 64 * 10; c += 256) {
        int tl = c / 10, a = c % 10;
        long gq = (long)(t0 + tl) * QKV_N + h * HDIM + a * 4;
        bf16x4 q1 = *(const bf16x4*)(qkv + gq);
        bf16x4 q2 = *(const bf16x4*)(qkv + gq + 40);
        bf16x4 k1 = *(const bf16x4*)(qkv + gq + DIM);
        bf16x4 k2 = *(const bf16x4*)(qkv + gq + DIM + 40);
        float4 rv = *(const float4*)(rot + (long)(t0 + tl) * 40 + a * 4);
        float rr[4] = {rv.x, rv.y, rv.z, rv.w};
        bf16x4 oq1, oq2, ok1, ok2;
#pragma unroll
        for (int j = 0; j < 4; j++) {
            float c_, s_;
            __sincosf(rr[j], &s_, &c_);
            float x1 = (float)q1[j], x2 = (float)q2[j];
            oq1[j] = (bf16_t)((x1 * c_ - x2 * s_) * SCL);
            oq2[j] = (bf16_t)((x2 * c_ + x1 * s_) * SCL);
            x1 = (float)k1[j]; x2 = (float)k2[j];
            ok1[j] = (bf16_t)(x1 * c_ - x2 * s_);
            ok2[j] = (bf16_t)(x2 * c_ + x1 * s_);
        }
        long o = ((long)h * NTOK + t0 + tl) * 96 + a * 4;
        *(bf16x4*)(Qd + o) = oq1;
        *(bf16x4*)(Qd + o + 40) = oq2;
        *(bf16x4*)(Kd + o) = ok1;
        *(bf16x4*)(Kd + o + 40) = ok2;
    }
    {
        bf16x8 z;
#pragma unroll
        for (int j = 0; j < 8; j++) z[j] = (bf16_t)0.f;
        for (int c = tid; c < 64 * 2; c += 256) {
            int tl = c / 2, a = c % 2;
            long o = ((long)h * NTOK + t0 + tl) * 96 + 80 + a * 8;
            *(bf16x8*)(Qd + o) = z;
            *(bf16x8*)(Kd + o) = z;
        }
    }
    __syncthreads();

    for (int c = tid; c < 80 * 8; c += 256) {
        int d = c / 8, tc = c % 8;
        bf16x8 v;
#pragma unroll
        for (int j = 0; j < 8; j++) v[j] = tv[(tc * 8 + j) * 88 + d];
        *(bf16x8*)(Vt + ((long)h * HDIM + d) * NTOK + t0 + tc * 8) = v;
    }
}

// ---------------- reduce: out = res + bias + sum_z p_z ----------------
template <int NP>
__global__ void reduceN(const float* __restrict__ p, const float* __restrict__ b,
                        const float* __restrict__ res, float* __restrict__ out) {
    long i = (long)blockIdx.x * blockDim.x + threadIdx.x;  // float4 index
    float4 r = ((const float4*)res)[i];
    int c4 = (int)(i % (DIM / 4)) * 4;
    float4 bv = *(const float4*)(b + c4);
    float ax = r.x + bv.x, ay = r.y + bv.y, az = r.z + bv.z, aw = r.w + bv.w;
#pragma unroll
    for (int z = 0; z < NP; z++) {
        float4 a = ((const float4*)p)[i + (long)z * NTOK * DIM / 4];
        ax += a.x; ay += a.y; az += a.z; aw += a.w;
    }
    float4 o = {ax, ay, az, aw};
    ((float4*)out)[i] = o;
}

// ---------------- GEMM: C[M,N] = A[M,K] * B[N,K]^T (+epilogue) -----------------
// 128x128 tile, 4 waves (2M x 2N), BK=32. 2 LDS bufs x 16KB = 32KB.
// LDS cap => 5 blocks/CU; natural VGPR (~68) keeps that occupancy WITHOUT a
// tight launch_bounds cap (R13's (256,5) forced ~102-VGPR budget -> acc spill,
// 645MB scratch writes, 6% MfmaUtil). Depth-1 prefetch: entry vmcnt(0)+barrier,
// stage(t+1) after barrier, 8 ds_read_b128 + 16 MFMA, compiler-managed lgkm.
// 64B rows; swizzle colb ^= (((row>>1)&3)<<4) both-sides (verified 0 conflicts).
// EPI 0: bf16=acc+bias | 1: f32=res+acc+bias | 2: bf16=qgelu(acc+bias) | 3: f32 partial
template <int EPI>
__global__ __launch_bounds__(256, 3) void gemmR(const bf16_t* __restrict__ A,
                                                const bf16_t* __restrict__ B,
                                                const float* __restrict__ bias,
                                                const float* __restrict__ res,
                                                void* __restrict__ Cv,
                                                int M, int N, int K, int kspl) {
    __shared__ char lds[2 * 16384];  // 32 KB
    const int tid = threadIdx.x;
    const int lane = tid & 63;
    const int l15 = lane & 15;
    const int g = lane >> 4;
    const int wid = tid >> 6;   // 0..3
    const int wr = wid >> 1;    // 0..1 (M)
    const int wc = wid & 1;     // 0..1 (N)

    // XCD-bijective block swizzle (x*y grid size % 8 == 0 for all launches)
    const int nx = gridDim.x;
    const int id = blockIdx.y * nx + blockIdx.x;
    const int cpx = (nx * gridDim.y) >> 3;
    const int sid = (id & 7) * cpx + (id >> 3);
    const int m0 = (sid / nx) * 128;
    const int n0 = (sid % nx) * 128;
    const int k0 = blockIdx.z * kspl;
    const int NT = kspl >> 5;  // K-tiles of 32

    // staging maps: per-lane global source pre-swizzled; LDS dest linear.
    const bf16_t *gA[2], *gB[2];
    int lAo[2], lBo[2];
#pragma unroll
    for (int j = 0; j < 2; j++) {
        int off = j * 4096 + tid * 16;                  // byte offset in 8KB region
        int row = off >> 6;                             // 0..127 (64B rows)
        int cb = (off & 63) ^ (((row >> 1) & 3) << 4);  // swizzled byte col
        gA[j] = A + (long)(m0 + row) * K + k0 + (cb >> 1);
        gB[j] = B + (long)(n0 + row) * K + k0 + (cb >> 1);
        lAo[j] = j * 4096 + wid * 1024;
        lBo[j] = 8192 + j * 4096 + wid * 1024;
    }

    f32x4 acc[4][4];
#pragma unroll
    for (int i = 0; i < 4; i++)
#pragma unroll
        for (int j = 0; j < 4; j++) acc[i][j] = (f32x4){0.f, 0.f, 0.f, 0.f};

    auto stage = [&](int buf, int t) {
        char* sb = lds + buf * 16384;
#pragma unroll
        for (int j = 0; j < 2; j++) GLOAD_LDS16(gA[j] + t * 32, sb + lAo[j]);
#pragma unroll
        for (int j = 0; j < 2; j++) GLOAD_LDS16(gB[j] + t * 32, sb + lBo[j]);
    };

    stage(0, 0);

    for (int t = 0; t < NT; ++t) {
        // tile t's 4 loads are the only outstanding VMEM; drain + publish.
        asm volatile("s_waitcnt vmcnt(0)\n\ts_barrier" ::: "memory");
        if (t + 1 < NT) stage((t + 1) & 1, t + 1);

        const char* pA = lds + (t & 1) * 16384;
        const char* pB = pA + 8192;
        bf16x8 af[4], bb[4];
#pragma unroll
        for (int m = 0; m < 4; m++) {
            int r = wr * 64 + m * 16 + l15;
            af[m] = *(const bf16x8*)(pA + r * 64 + ((g * 16) ^ (((r >> 1) & 3) << 4)));
        }
#pragma unroll
        for (int n = 0; n < 4; n++) {
            int r = wc * 64 + n * 16 + l15;
            bb[n] = *(const bf16x8*)(pB + r * 64 + ((g * 16) ^ (((r >> 1) & 3) << 4)));
        }
        __builtin_amdgcn_s_setprio(1);
#pragma unroll
        for (int m = 0; m < 4; m++)
#pragma unroll
            for (int n = 0; n < 4; n++)
                acc[m][n] = __builtin_amdgcn_mfma_f32_16x16x32_bf16(af[m], bb[n],
                                                                    acc[m][n], 0, 0, 0);
        __builtin_amdgcn_s_setprio(0);
    }

    // epilogue: D row = (lane>>4)*4 + rr, col = lane&15
#pragma unroll
    for (int m = 0; m < 4; m++)
#pragma unroll
        for (int n = 0; n < 4; n++) {
            const int col = n0 + wc * 64 + n * 16 + l15;
            const float bv = (EPI == 3) ? 0.f : bias[col];
#pragma unroll
            for (int rr = 0; rr < 4; rr++) {
                const int row = m0 + wr * 64 + m * 16 + g * 4 + rr;
                const long idx = (long)row * N + col;
                float val = acc[m][n][rr] + bv;
                if (EPI == 0) {
                    ((bf16_t*)Cv)[idx] = (bf16_t)val;
                } else if (EPI == 1) {
                    ((float*)Cv)[idx] = res[idx] + val;
                } else if (EPI == 2) {
                    float ge = val / (1.f + __expf(-1.702f * val));
                    ((bf16_t*)Cv)[idx] = (bf16_t)ge;
                } else {
                    ((float*)Cv)[(long)blockIdx.z * M * N + idx] = val;
                }
            }
        }
}

// ---------------- Flash attention v3: no-max softmax (unchanged from R12) ----
__global__ __launch_bounds__(256) void attn_kernel(const bf16_t* __restrict__ Qd,
                                                   const bf16_t* __restrict__ Kd,
                                                   const bf16_t* __restrict__ Vt,
                                                   const int* __restrict__ cu,
                                                   int ncu,
                                                   bf16_t* __restrict__ out) {
    __shared__ bf16_t lK[64 * 104];   // [k][d], stride 104
    __shared__ bf16_t lV[96 * 64];    // [d][k], 128B rows + XOR swizzle
    __shared__ bf16_t lP[4 * 16 * 72];

    const int tid = threadIdx.x;
    const int lane = tid & 63;
    const int l15 = lane & 15;
    const int g = lane >> 4;
    const int wid = tid >> 6;
    const int h = blockIdx.y;
    const int q0 = blockIdx.x * 64;

    int sseg = 0;
    for (int j = 1; j < ncu - 1; j++) if (q0 >= cu[j]) sseg = j;
    const int kbeg = cu[sseg], kend = cu[sseg + 1];

    bf16x8 aq[3];
    {
        const bf16_t* qp = Qd + ((long)h * NTOK + q0 + wid * 16 + l15) * 96;
#pragma unroll
        for (int ks = 0; ks < 3; ks++)
            aq[ks] = *(const bf16x8*)(qp + ks * 32 + g * 8);
    }

    for (int c = tid; c < 16 * 8; c += 256) {
        int d = 80 + c / 8, a = c % 8;
        bf16x8 v;
#pragma unroll
        for (int j = 0; j < 8; j++) v[j] = (d == 80) ? (bf16_t)1.f : (bf16_t)0.f;
        *(bf16x8*)((char*)lV + d * 128 + ((a * 16) ^ ((d & 7) << 4))) = v;
    }

    f32x4 o[6];
#pragma unroll
    for (int n = 0; n < 6; n++) o[n] = (f32x4){0.f, 0.f, 0.f, 0.f};

    bf16x8 rK[3], rV[3];
    auto ldK = [&](int kt) {
#pragma unroll
        for (int i = 0; i < 3; i++) {
            int c = tid + i * 256;
            int row = c / 12, c16 = c % 12;
            rK[i] = *(const bf16x8*)(Kd + ((long)h * NTOK + kt + row) * 96 + c16 * 8);
        }
    };
    auto ldV = [&](int kt) {
#pragma unroll
        for (int i = 0; i < 3; i++) {
            int c = tid + i * 256;
            if (c < 640) {
                int d = c / 8, a = c % 8;
                rV[i] = *(const bf16x8*)(Vt + ((long)h * HDIM + d) * NTOK + kt + a * 8);
            }
        }
    };
    auto wrKV = [&]() {
#pragma unroll
        for (int i = 0; i < 3; i++) {
            int c = tid + i * 256;
            int row = c / 12, c16 = c % 12;
            *(bf16x8*)(lK + row * 104 + c16 * 8) = rK[i];
        }
#pragma unroll
        for (int i = 0; i < 3; i++) {
            int c = tid + i * 256;
            if (c < 640) {
                int d = c / 8, a = c % 8;
                *(bf16x8*)((char*)lV + d * 128 + ((a * 16) ^ ((d & 7) << 4))) = rV[i];
            }
        }
    };

    ldK(kbeg); ldV(kbeg);
    wrKV();
    __syncthreads();

    for (int kt = kbeg; kt < kend; kt += 64) {
        const bool more = (kt + 64 < kend);
        if (more) { ldK(kt + 64); ldV(kt + 64); }

        f32x4 s[4];
#pragma unroll
        for (int n = 0; n < 4; n++) s[n] = (f32x4){0.f, 0.f, 0.f, 0.f};
#pragma unroll
        for (int n = 0; n < 4; n++)
#pragma unroll
            for (int ks = 0; ks < 3; ks++) {
                bf16x8 kf = *(const bf16x8*)(lK + (n * 16 + l15) * 104 + ks * 32 + g * 8);
                s[n] = __builtin_amdgcn_mfma_f32_16x16x32_bf16(aq[ks], kf, s[n], 0, 0, 0);
            }

#pragma unroll
        for (int n = 0; n < 4; n++)
#pragma unroll
            for (int r = 0; r < 4; r++)
                lP[wid * 1152 + (g * 4 + r) * 72 + n * 16 + l15] = (bf16_t)exp2f(s[n][r]);

        asm volatile("s_waitcnt lgkmcnt(0)" ::: "memory");
        bf16x8 pa[2];
#pragma unroll
        for (int ks = 0; ks < 2; ks++)
            pa[ks] = *(const bf16x8*)(lP + wid * 1152 + l15 * 72 + ks * 32 + g * 8);
#pragma unroll
        for (int n = 0; n < 6; n++)
#pragma unroll
            for (int ks = 0; ks < 2; ks++) {
                int rv = n * 16 + l15;
                bf16x8 vb = *(const bf16x8*)((char*)lV + rv * 128 +
                                             ((ks * 64 + g * 16) ^ ((rv & 7) << 4)));
                o[n] = __builtin_amdgcn_mfma_f32_16x16x32_bf16(pa[ks], vb, o[n], 0, 0, 0);
            }
        __syncthreads();
        if (more) wrKV();
        __syncthreads();
    }

    float lI[4];
#pragma unroll
    for (int r = 0; r < 4; r++) lI[r] = __shfl(o[5][r], lane & 48, 64);

#pragma unroll
    for (int n = 0; n < 5; n++)
#pragma unroll
        for (int r = 0; r < 4; r++) {
            int row = q0 + wid * 16 + g * 4 + r;
            out[(long)row * DIM + h * HDIM + n * 16 + l15] = (bf16_t)(o[n][r] / lI[r]);
        }
}

// ---------------- launch ----------------
extern "C" void kernel_launch(void* const* d_in, const int* in_sizes, int n_in,
                              void* d_out, int out_size, void* d_ws, size_t ws_size,
                              hipStream_t stream) {
    const float* hidden = (const float*)d_in[0];
    const float* rot    = (const float*)d_in[1];
    const int*   cu     = (const int*)d_in[2];
    const float* n1w    = (const float*)d_in[3];
    const float* n1b    = (const float*)d_in[4];
    const float* n2w    = (const float*)d_in[5];
    const float* n2b    = (const float*)d_in[6];
    const float* qkv_w  = (const float*)d_in[7];
    const float* qkv_b  = (const float*)d_in[8];
    const float* proj_w = (const float*)d_in[9];
    const float* proj_b = (const float*)d_in[10];
    const float* fc1_w  = (const float*)d_in[11];
    const float* fc1_b  = (const float*)d_in[12];
    const float* fc2_w  = (const float*)d_in[13];
    const float* fc2_b  = (const float*)d_in[14];
    float* outp = (float*)d_out;

    char* ws = (char*)d_ws;
    bf16_t* w2   = (bf16_t*)(ws);                  // [0,13.1M)        cvt->FC2
    bf16_t* w1   = (bf16_t*)(ws + 13107200);       // [13.1M,26.2M)    cvt->FC1
    bf16_t* wp   = (bf16_t*)(ws + 26214400);       // [26.2M,29.5M)    cvt->proj
    bf16_t* wq   = (bf16_t*)(ws + 29491200);       // [29.5M,39.3M)    cvt->QKV
    bf16_t* xln  = (bf16_t*)(ws + 39321600);       // [39.3M,49.8M)    LN1->QKV, LN2->FC1
    bf16_t* qkvb = (bf16_t*)(ws + 49807360);       // [49.8M,81.3M)    QKV->prep
    bf16_t* Qd   = (bf16_t*)(ws + 81264640);       // [81.3M,93.8M)    prep->attn
    bf16_t* Kd   = (bf16_t*)(ws + 93847552);       // [93.8M,106.4M)   prep->attn
    bf16_t* Vt   = (bf16_t*)(ws + 106430464);      // [106.4M,116.9M)  prep->attn
    bf16_t* attno= (bf16_t*)(ws + 116916224);      // [116.9M,127.4M)  attn->proj
    bf16_t* act  = (bf16_t*)(ws + 49807360);       // [49.8M,91.75M)   FC1->FC2 (qkvb/Qd dead)
    float*  p01  = (float*)(ws + 91750400);        // [91.75M,133.69M) FC2 partials x2
    // h (f32) lives in d_out: proj writes (EPI1), LN2 reads, FC2-reduce accumulates.

    int ncu = in_sizes[2];

    cvt_f32_bf16<<<2048, 256, 0, stream>>>(qkv_w, wq, QKV_N * DIM);
    cvt_f32_bf16<<<1024, 256, 0, stream>>>(proj_w, wp, DIM * DIM);
    cvt_f32_bf16<<<2048, 256, 0, stream>>>(fc1_w, w1, MLP * DIM);
    cvt_f32_bf16<<<2048, 256, 0, stream>>>(fc2_w, w2, DIM * MLP);

    ln_kernel<<<NTOK, 256, 0, stream>>>(hidden, n1w, n1b, xln);
    // QKV: 4096x3840x1280 -> 30x32 = 960 blocks, NT=40
    gemmR<0><<<dim3(QKV_N / 128, NTOK / 128, 1), 256, 0, stream>>>(
        xln, wq, qkv_b, nullptr, qkvb, NTOK, QKV_N, DIM, DIM);
    prep_kernel<<<dim3(NTOK / 64, NHEADS), 256, 0, stream>>>(qkvb, rot, Qd, Kd, Vt);
    attn_kernel<<<dim3(NTOK / 64, NHEADS), 256, 0, stream>>>(Qd, Kd, Vt, cu, ncu, attno);
    // proj: 4096x1280x1280 -> 10x32 = 320 blocks, NT=40, direct h = hidden+acc+bias
    gemmR<1><<<dim3(DIM / 128, NTOK / 128, 1), 256, 0, stream>>>(
        attno, wp, proj_b, hidden, outp, NTOK, DIM, DIM, DIM);
    ln_kernel<<<NTOK, 256, 0, stream>>>(outp, n2w, n2b, xln);
    // FC1: 40x32 = 1280 blocks, NT=40
    gemmR<2><<<dim3(MLP / 128, NTOK / 128, 1), 256, 0, stream>>>(
        xln, w1, fc1_b, nullptr, act, NTOK, MLP, DIM, DIM);
    // FC2: split-K x2 -> 10x32x2 = 640 blocks, NT=80
    gemmR<3><<<dim3(DIM / 128, NTOK / 128, 2), 256, 0, stream>>>(
        act, w2, nullptr, nullptr, p01, NTOK, DIM, MLP, 2560);
    reduceN<2><<<NTOK * DIM / 4 / 256, 256, 0, stream>>>(p01, fc2_b, outp, outp);
}

// Round 15
// 343.830 us; speedup vs baseline: 2.4012x; 1.0169x over previous
//
#include <hip/hip_runtime.h>
#include <hip/hip_bf16.h>

// Qwen2VL vision block, MI355X gfx950.
// R15: GEMM reverted to R12 config (3x16KB bufs, counted vmcnt(4) depth-2,
//      (256,3) — best measured: FC1 96us). cvt x4 fused into one kernel.

typedef __bf16 bf16_t;
typedef bf16_t bf16x8 __attribute__((ext_vector_type(8)));
typedef bf16_t bf16x4 __attribute__((ext_vector_type(4)));
typedef float f32x4 __attribute__((ext_vector_type(4)));

#define DIM 1280
#define NHEADS 16
#define HDIM 80
#define MLP 5120
#define NTOK 4096
#define QKV_N 3840

#define GLOAD_LDS16(gp, lp)                                                          \
    __builtin_amdgcn_global_load_lds((const __attribute__((address_space(1))) void*)(gp), \
                                     (__attribute__((address_space(3))) void*)(lp), 16, 0, 0)

// ---------------- fused fp32 -> bf16 conversion of all 4 weight tensors ------
__global__ void cvt_all(const float* __restrict__ s0, const float* __restrict__ s1,
                        const float* __restrict__ s2, const float* __restrict__ s3,
                        bf16_t* __restrict__ d0, bf16_t* __restrict__ d1,
                        bf16_t* __restrict__ d2, bf16_t* __restrict__ d3,
                        int n0, int n1, int n2, int n3) {
    // segment sizes in float4 units; n_i divisible by 4
    int q0 = n0 >> 2, q1 = n1 >> 2, q2 = n2 >> 2, q3 = n3 >> 2;
    int total = q0 + q1 + q2 + q3;
    for (int i = blockIdx.x * blockDim.x + threadIdx.x; i < total;
         i += gridDim.x * blockDim.x) {
        const float* src;
        bf16_t* dst;
        int j = i;
        if (j < q0) { src = s0; dst = d0; }
        else if ((j -= q0) < q1) { src = s1; dst = d1; }
        else if ((j -= q1) < q2) { src = s2; dst = d2; }
        else { j -= q2; src = s3; dst = d3; }
        float4 v = ((const float4*)src)[j];
        bf16x4 o;
        o[0] = (bf16_t)v.x; o[1] = (bf16_t)v.y; o[2] = (bf16_t)v.z; o[3] = (bf16_t)v.w;
        *(bf16x4*)(dst + j * 4) = o;
    }
}

// ---------------- LayerNorm (fp32 in, bf16 out) ----------------
__global__ __launch_bounds__(256) void ln_kernel(const float* __restrict__ x,
                                                 const float* __restrict__ w,
                                                 const float* __restrict__ b,
                                                 bf16_t* __restrict__ out) {
    int row = blockIdx.x;
    const float* xr = x + (long)row * DIM;
    float v[5];
    float s = 0.f, ss = 0.f;
#pragma unroll
    for (int j = 0; j < 5; j++) {
        v[j] = xr[j * 256 + threadIdx.x];
        s += v[j];
        ss += v[j] * v[j];
    }
#pragma unroll
    for (int off = 32; off > 0; off >>= 1) {
        s += __shfl_xor(s, off, 64);
        ss += __shfl_xor(ss, off, 64);
    }
    __shared__ float red[8];
    int wid = threadIdx.x >> 6;
    if ((threadIdx.x & 63) == 0) { red[wid] = s; red[wid + 4] = ss; }
    __syncthreads();
    s = red[0] + red[1] + red[2] + red[3];
    ss = red[4] + red[5] + red[6] + red[7];
    float mean = s * (1.f / DIM);
    float var = ss * (1.f / DIM) - mean * mean;
    float rstd = rsqrtf(var + 1e-6f);
    bf16_t* orow = out + (long)row * DIM;
#pragma unroll
    for (int j = 0; j < 5; j++) {
        int d = j * 256 + threadIdx.x;
        orow[d] = (bf16_t)((v[j] - mean) * rstd * w[d] + b[d]);
    }
}

// ---------------- prep: fused RoPE + layouts; Q pre-scaled by scale*log2e ----
__global__ __launch_bounds__(256) void prep_kernel(const bf16_t* __restrict__ qkv,
                                                   const float* __restrict__ rot,
                                                   bf16_t* __restrict__ Qd,
                                                   bf16_t* __restrict__ Kd,
                                                   bf16_t* __restrict__ Vt) {
    const float SCL = 0.11180339887498949f * 1.4426950408889634f;  // 1/sqrt(80)*log2(e)
    __shared__ bf16_t tv[64 * 88];
    const int tid = threadIdx.x;
    const int t0 = blockIdx.x * 64;
    const int h = blockIdx.y;

    for (int c = tid; c < 64 * 10; c += 256) {
        int tl = c / 10, a = c % 10;
        bf16x8 v = *(const bf16x8*)(qkv + (long)(t0 + tl) * QKV_N + 2 * DIM + h * HDIM + a * 8);
        *(bf16x8*)(tv + tl * 88 + a * 8) = v;
    }

    for (int c = tid; c < 64 * 10; c += 256) {
        int tl = c / 10, a = c % 10;
        long gq = (long)(t0 + tl) * QKV_N + h * HDIM + a * 4;
        bf16x4 q1 = *(const bf16x4*)(qkv + gq);
        bf16x4 q2 = *(const bf16x4*)(qkv + gq + 40);
        bf16x4 k1 = *(const bf16x4*)(qkv + gq + DIM);
        bf16x4 k2 = *(const bf16x4*)(qkv + gq + DIM + 40);
        float4 rv = *(const float4*)(rot + (long)(t0 + tl) * 40 + a * 4);
        float rr[4] = {rv.x, rv.y, rv.z, rv.w};
        bf16x4 oq1, oq2, ok1, ok2;
#pragma unroll
        for (int j = 0; j < 4; j++) {
            float c_, s_;
            __sincosf(rr[j], &s_, &c_);
            float x1 = (float)q1[j], x2 = (float)q2[j];
            oq1[j] = (bf16_t)((x1 * c_ - x2 * s_) * SCL);
            oq2[j] = (bf16_t)((x2 * c_ + x1 * s_) * SCL);
            x1 = (float)k1[j]; x2 = (float)k2[j];
            ok1[j] = (bf16_t)(x1 * c_ - x2 * s_);
            ok2[j] = (bf16_t)(x2 * c_ + x1 * s_);
        }
        long o = ((long)h * NTOK + t0 + tl) * 96 + a * 4;
        *(bf16x4*)(Qd + o) = oq1;
        *(bf16x4*)(Qd + o + 40) = oq2;
        *(bf16x4*)(Kd + o) = ok1;
        *(bf16x4*)(Kd + o + 40) = ok2;
    }
    {
        bf16x8 z;
#pragma unroll
        for (int j = 0; j < 8; j++) z[j] = (bf16_t)0.f;
        for (int c = tid; c < 64 * 2; c += 256) {
            int tl = c / 2, a = c % 2;
            long o = ((long)h * NTOK + t0 + tl) * 96 + 80 + a * 8;
            *(bf16x8*)(Qd + o) = z;
            *(bf16x8*)(Kd + o) = z;
        }
    }
    __syncthreads();

    for (int c = tid; c < 80 * 8; c += 256) {
        int d = c / 8, tc = c % 8;
        bf16x8 v;
#pragma unroll
        for (int j = 0; j < 8; j++) v[j] = tv[(tc * 8 + j) * 88 + d];
        *(bf16x8*)(Vt + ((long)h * HDIM + d) * NTOK + t0 + tc * 8) = v;
    }
}

// ---------------- reduce: out = res + bias + sum_z p_z ----------------
template <int NP>
__global__ void reduceN(const float* __restrict__ p, const float* __restrict__ b,
                        const float* __restrict__ res, float* __restrict__ out) {
    long i = (long)blockIdx.x * blockDim.x + threadIdx.x;  // float4 index
    float4 r = ((const float4*)res)[i];
    int c4 = (int)(i % (DIM / 4)) * 4;
    float4 bv = *(const float4*)(b + c4);
    float ax = r.x + bv.x, ay = r.y + bv.y, az = r.z + bv.z, aw = r.w + bv.w;
#pragma unroll
    for (int z = 0; z < NP; z++) {
        float4 a = ((const float4*)p)[i + (long)z * NTOK * DIM / 4];
        ax += a.x; ay += a.y; az += a.z; aw += a.w;
    }
    float4 o = {ax, ay, az, aw};
    ((float4*)out)[i] = o;
}

// ---------------- GEMM: C[M,N] = A[M,K] * B[N,K]^T (+epilogue) -----------------
// R12 config (measured best): 128x128 tile, 4 waves, BK=32, 3 bufs x 16KB
// (48KB -> 3 blocks/CU), depth-2 counted pipeline: entry vmcnt(4) (tile t's
// 4 loads landed, t+1's 4 in flight), ONE barrier/tile, stage(t+2) after
// barrier. Compiler-managed lgkm. 64B rows, swizzle colb ^= (((row>>1)&3)<<4)
// both-sides (verified 0 conflicts).
// EPI 0: bf16=acc+bias | 1: f32=res+acc+bias | 2: bf16=qgelu(acc+bias) | 3: f32 partial
template <int EPI>
__global__ __launch_bounds__(256, 3) void gemmR(const bf16_t* __restrict__ A,
                                                const bf16_t* __restrict__ B,
                                                const float* __restrict__ bias,
                                                const float* __restrict__ res,
                                                void* __restrict__ Cv,
                                                int M, int N, int K, int kspl) {
    __shared__ char lds[3 * 16384];  // 48 KB
    const int tid = threadIdx.x;
    const int lane = tid & 63;
    const int l15 = lane & 15;
    const int g = lane >> 4;
    const int wid = tid >> 6;   // 0..3
    const int wr = wid >> 1;    // 0..1 (M)
    const int wc = wid & 1;     // 0..1 (N)

    // XCD-bijective block swizzle (x*y grid size % 8 == 0 for all launches)
    const int nx = gridDim.x;
    const int id = blockIdx.y * nx + blockIdx.x;
    const int cpx = (nx * gridDim.y) >> 3;
    const int sid = (id & 7) * cpx + (id >> 3);
    const int m0 = (sid / nx) * 128;
    const int n0 = (sid % nx) * 128;
    const int k0 = blockIdx.z * kspl;
    const int NT = kspl >> 5;  // K-tiles of 32

    // staging maps: per-lane global source pre-swizzled; LDS dest linear.
    const bf16_t *gA[2], *gB[2];
    int lAo[2], lBo[2];
#pragma unroll
    for (int j = 0; j < 2; j++) {
        int off = j * 4096 + tid * 16;                  // byte offset in 8KB region
        int row = off >> 6;                             // 0..127 (64B rows)
        int cb = (off & 63) ^ (((row >> 1) & 3) << 4);  // swizzled byte col
        gA[j] = A + (long)(m0 + row) * K + k0 + (cb >> 1);
        gB[j] = B + (long)(n0 + row) * K + k0 + (cb >> 1);
        lAo[j] = j * 4096 + wid * 1024;
        lBo[j] = 8192 + j * 4096 + wid * 1024;
    }

    f32x4 acc[4][4];
#pragma unroll
    for (int i = 0; i < 4; i++)
#pragma unroll
        for (int j = 0; j < 4; j++) acc[i][j] = (f32x4){0.f, 0.f, 0.f, 0.f};

    auto stage = [&](int buf, int t) {
        char* sb = lds + buf * 16384;
#pragma unroll
        for (int j = 0; j < 2; j++) GLOAD_LDS16(gA[j] + t * 32, sb + lAo[j]);
#pragma unroll
        for (int j = 0; j < 2; j++) GLOAD_LDS16(gB[j] + t * 32, sb + lBo[j]);
    };

    stage(0, 0);
    stage(1, 1);

    int buf = 0;
    for (int t = 0; t < NT; ++t) {
        if (t < NT - 1)
            asm volatile("s_waitcnt vmcnt(4)\n\ts_barrier" ::: "memory");
        else
            asm volatile("s_waitcnt vmcnt(0)\n\ts_barrier" ::: "memory");
        if (t + 2 < NT) stage((buf + 2) % 3, t + 2);

        const char* pA = lds + buf * 16384;
        const char* pB = pA + 8192;
        bf16x8 af[4], bb[4];
#pragma unroll
        for (int m = 0; m < 4; m++) {
            int r = wr * 64 + m * 16 + l15;
            af[m] = *(const bf16x8*)(pA + r * 64 + ((g * 16) ^ (((r >> 1) & 3) << 4)));
        }
#pragma unroll
        for (int n = 0; n < 4; n++) {
            int r = wc * 64 + n * 16 + l15;
            bb[n] = *(const bf16x8*)(pB + r * 64 + ((g * 16) ^ (((r >> 1) & 3) << 4)));
        }
        __builtin_amdgcn_s_setprio(1);
#pragma unroll
        for (int m = 0; m < 4; m++)
#pragma unroll
            for (int n = 0; n < 4; n++)
                acc[m][n] = __builtin_amdgcn_mfma_f32_16x16x32_bf16(af[m], bb[n],
                                                                    acc[m][n], 0, 0, 0);
        __builtin_amdgcn_s_setprio(0);
        buf = (buf + 1) % 3;
    }

    // epilogue: D row = (lane>>4)*4 + rr, col = lane&15
#pragma unroll
    for (int m = 0; m < 4; m++)
#pragma unroll
        for (int n = 0; n < 4; n++) {
            const int col = n0 + wc * 64 + n * 16 + l15;
            const float bv = (EPI == 3) ? 0.f : bias[col];
#pragma unroll
            for (int rr = 0; rr < 4; rr++) {
                const int row = m0 + wr * 64 + m * 16 + g * 4 + rr;
                const long idx = (long)row * N + col;
                float val = acc[m][n][rr] + bv;
                if (EPI == 0) {
                    ((bf16_t*)Cv)[idx] = (bf16_t)val;
                } else if (EPI == 1) {
                    ((float*)Cv)[idx] = res[idx] + val;
                } else if (EPI == 2) {
                    float ge = val / (1.f + __expf(-1.702f * val));
                    ((bf16_t*)Cv)[idx] = (bf16_t)ge;
                } else {
                    ((float*)Cv)[(long)blockIdx.z * M * N + idx] = val;
                }
            }
        }
}

// ---------------- Flash attention v3: no-max softmax (unchanged) ----------------
__global__ __launch_bounds__(256) void attn_kernel(const bf16_t* __restrict__ Qd,
                                                   const bf16_t* __restrict__ Kd,
                                                   const bf16_t* __restrict__ Vt,
                                                   const int* __restrict__ cu,
                                                   int ncu,
                                                   bf16_t* __restrict__ out) {
    __shared__ bf16_t lK[64 * 104];   // [k][d], stride 104
    __shared__ bf16_t lV[96 * 64];    // [d][k], 128B rows + XOR swizzle
    __shared__ bf16_t lP[4 * 16 * 72];

    const int tid = threadIdx.x;
    const int lane = tid & 63;
    const int l15 = lane & 15;
    const int g = lane >> 4;
    const int wid = tid >> 6;
    const int h = blockIdx.y;
    const int q0 = blockIdx.x * 64;

    int sseg = 0;
    for (int j = 1; j < ncu - 1; j++) if (q0 >= cu[j]) sseg = j;
    const int kbeg = cu[sseg], kend = cu[sseg + 1];

    bf16x8 aq[3];
    {
        const bf16_t* qp = Qd + ((long)h * NTOK + q0 + wid * 16 + l15) * 96;
#pragma unroll
        for (int ks = 0; ks < 3; ks++)
            aq[ks] = *(const bf16x8*)(qp + ks * 32 + g * 8);
    }

    for (int c = tid; c < 16 * 8; c += 256) {
        int d = 80 + c / 8, a = c % 8;
        bf16x8 v;
#pragma unroll
        for (int j = 0; j < 8; j++) v[j] = (d == 80) ? (bf16_t)1.f : (bf16_t)0.f;
        *(bf16x8*)((char*)lV + d * 128 + ((a * 16) ^ ((d & 7) << 4))) = v;
    }

    f32x4 o[6];
#pragma unroll
    for (int n = 0; n < 6; n++) o[n] = (f32x4){0.f, 0.f, 0.f, 0.f};

    bf16x8 rK[3], rV[3];
    auto ldK = [&](int kt) {
#pragma unroll
        for (int i = 0; i < 3; i++) {
            int c = tid + i * 256;
            int row = c / 12, c16 = c % 12;
            rK[i] = *(const bf16x8*)(Kd + ((long)h * NTOK + kt + row) * 96 + c16 * 8);
        }
    };
    auto ldV = [&](int kt) {
#pragma unroll
        for (int i = 0; i < 3; i++) {
            int c = tid + i * 256;
            if (c < 640) {
                int d = c / 8, a = c % 8;
                rV[i] = *(const bf16x8*)(Vt + ((long)h * HDIM + d) * NTOK + kt + a * 8);
            }
        }
    };
    auto wrKV = [&]() {
#pragma unroll
        for (int i = 0; i < 3; i++) {
            int c = tid + i * 256;
            int row = c / 12, c16 = c % 12;
            *(bf16x8*)(lK + row * 104 + c16 * 8) = rK[i];
        }
#pragma unroll
        for (int i = 0; i < 3; i++) {
            int c = tid + i * 256;
            if (c < 640) {
                int d = c / 8, a = c % 8;
                *(bf16x8*)((char*)lV + d * 128 + ((a * 16) ^ ((d & 7) << 4))) = rV[i];
            }
        }
    };

    ldK(kbeg); ldV(kbeg);
    wrKV();
    __syncthreads();

    for (int kt = kbeg; kt < kend; kt += 64) {
        const bool more = (kt + 64 < kend);
        if (more) { ldK(kt + 64); ldV(kt + 64); }

        f32x4 s[4];
#pragma unroll
        for (int n = 0; n < 4; n++) s[n] = (f32x4){0.f, 0.f, 0.f, 0.f};
#pragma unroll
        for (int n = 0; n < 4; n++)
#pragma unroll
            for (int ks = 0; ks < 3; ks++) {
                bf16x8 kf = *(const bf16x8*)(lK + (n * 16 + l15) * 104 + ks * 32 + g * 8);
                s[n] = __builtin_amdgcn_mfma_f32_16x16x32_bf16(aq[ks], kf, s[n], 0, 0, 0);
            }

#pragma unroll
        for (int n = 0; n < 4; n++)
#pragma unroll
            for (int r = 0; r < 4; r++)
                lP[wid * 1152 + (g * 4 + r) * 72 + n * 16 + l15] = (bf16_t)exp2f(s[n][r]);

        asm volatile("s_waitcnt lgkmcnt(0)" ::: "memory");
        bf16x8 pa[2];
#pragma unroll
        for (int ks = 0; ks < 2; ks++)
            pa[ks] = *(const bf16x8*)(lP + wid * 1152 + l15 * 72 + ks * 32 + g * 8);
#pragma unroll
        for (int n = 0; n < 6; n++)
#pragma unroll
            for (int ks = 0; ks < 2; ks++) {
                int rv = n * 16 + l15;
                bf16x8 vb = *(const bf16x8*)((char*)lV + rv * 128 +
                                             ((ks * 64 + g * 16) ^ ((rv & 7) << 4)));
                o[n] = __builtin_amdgcn_mfma_f32_16x16x32_bf16(pa[ks], vb, o[n], 0, 0, 0);
            }
        __syncthreads();
        if (more) wrKV();
        __syncthreads();
    }

    float lI[4];
#pragma unroll
    for (int r = 0; r < 4; r++) lI[r] = __shfl(o[5][r], lane & 48, 64);

#pragma unroll
    for (int n = 0; n < 5; n++)
#pragma unroll
        for (int r = 0; r < 4; r++) {
            int row = q0 + wid * 16 + g * 4 + r;
            out[(long)row * DIM + h * HDIM + n * 16 + l15] = (bf16_t)(o[n][r] / lI[r]);
        }
}

// ---------------- launch ----------------
extern "C" void kernel_launch(void* const* d_in, const int* in_sizes, int n_in,
                              void* d_out, int out_size, void* d_ws, size_t ws_size,
                              hipStream_t stream) {
    const float* hidden = (const float*)d_in[0];
    const float* rot    = (const float*)d_in[1];
    const int*   cu     = (const int*)d_in[2];
    const float* n1w    = (const float*)d_in[3];
    const float* n1b    = (const float*)d_in[4];
    const float* n2w    = (const float*)d_in[5];
    const float* n2b    = (const float*)d_in[6];
    const float* qkv_w  = (const float*)d_in[7];
    const float* qkv_b  = (const float*)d_in[8];
    const float* proj_w = (const float*)d_in[9];
    const float* proj_b = (const float*)d_in[10];
    const float* fc1_w  = (const float*)d_in[11];
    const float* fc1_b  = (const float*)d_in[12];
    const float* fc2_w  = (const float*)d_in[13];
    const float* fc2_b  = (const float*)d_in[14];
    float* outp = (float*)d_out;

    char* ws = (char*)d_ws;
    bf16_t* w2   = (bf16_t*)(ws);                  // [0,13.1M)        cvt->FC2
    bf16_t* w1   = (bf16_t*)(ws + 13107200);       // [13.1M,26.2M)    cvt->FC1
    bf16_t* wp   = (bf16_t*)(ws + 26214400);       // [26.2M,29.5M)    cvt->proj
    bf16_t* wq   = (bf16_t*)(ws + 29491200);       // [29.5M,39.3M)    cvt->QKV
    bf16_t* xln  = (bf16_t*)(ws + 39321600);       // [39.3M,49.8M)    LN1->QKV, LN2->FC1
    bf16_t* qkvb = (bf16_t*)(ws + 49807360);       // [49.8M,81.3M)    QKV->prep
    bf16_t* Qd   = (bf16_t*)(ws + 81264640);       // [81.3M,93.8M)    prep->attn
    bf16_t* Kd   = (bf16_t*)(ws + 93847552);       // [93.8M,106.4M)   prep->attn
    bf16_t* Vt   = (bf16_t*)(ws + 106430464);      // [106.4M,116.9M)  prep->attn
    bf16_t* attno= (bf16_t*)(ws + 116916224);      // [116.9M,127.4M)  attn->proj
    bf16_t* act  = (bf16_t*)(ws + 49807360);       // [49.8M,91.75M)   FC1->FC2 (qkvb/Qd dead)
    float*  p01  = (float*)(ws + 91750400);        // [91.75M,133.69M) FC2 partials x2
    // h (f32) lives in d_out: proj writes (EPI1), LN2 reads, FC2-reduce accumulates.

    int ncu = in_sizes[2];

    cvt_all<<<2048, 256, 0, stream>>>(fc2_w, fc1_w, proj_w, qkv_w,
                                      w2, w1, wp, wq,
                                      DIM * MLP, MLP * DIM, DIM * DIM, QKV_N * DIM);

    ln_kernel<<<NTOK, 256, 0, stream>>>(hidden, n1w, n1b, xln);
    // QKV: 4096x3840x1280 -> 30x32 = 960 blocks, NT=40
    gemmR<0><<<dim3(QKV_N / 128, NTOK / 128, 1), 256, 0, stream>>>(
        xln, wq, qkv_b, nullptr, qkvb, NTOK, QKV_N, DIM, DIM);
    prep_kernel<<<dim3(NTOK / 64, NHEADS), 256, 0, stream>>>(qkvb, rot, Qd, Kd, Vt);
    attn_kernel<<<dim3(NTOK / 64, NHEADS), 256, 0, stream>>>(Qd, Kd, Vt, cu, ncu, attno);
    // proj: 4096x1280x1280 -> 10x32 = 320 blocks, NT=40, direct h = hidden+acc+bias
    gemmR<1><<<dim3(DIM / 128, NTOK / 128, 1), 256, 0, stream>>>(
        attno, wp, proj_b, hidden, outp, NTOK, DIM, DIM, DIM);
    ln_kernel<<<NTOK, 256, 0, stream>>>(outp, n2w, n2b, xln);
    // FC1: 40x32 = 1280 blocks, NT=40
    gemmR<2><<<dim3(MLP / 128, NTOK / 128, 1), 256, 0, stream>>>(
        xln, w1, fc1_b, nullptr, act, NTOK, MLP, DIM, DIM);
    // FC2: split-K x2 -> 10x32x2 = 640 blocks, NT=80
    gemmR<3><<<dim3(DIM / 128, NTOK / 128, 2), 256, 0, stream>>>(
        act, w2, nullptr, nullptr, p01, NTOK, DIM, MLP, 2560);
    reduceN<2><<<NTOK * DIM / 4 / 256, 256, 0, stream>>>(p01, fc2_b, outp, outp);
}

// Round 16
// 331.308 us; speedup vs baseline: 2.4920x; 1.0378x over previous
//
#include <hip/hip_runtime.h>
#include <hip/hip_bf16.h>

// Qwen2VL vision block, MI355X gfx950.
// R16: gemmS — 128x128 tile, 8 waves (2Mx4N, per-wave 64x32), 3x16KB bufs,
//      depth-2 counted vmcnt(2). Rationale: 5 schedules plateaued at ~23%
//      MfmaUtil with 12 waves/CU; halving per-wave regs doubles waves/CU
//      (16-24) for latency absorption. FC2 -> direct EPI1 (no split-K/reduce).

typedef __bf16 bf16_t;
typedef bf16_t bf16x8 __attribute__((ext_vector_type(8)));
typedef bf16_t bf16x4 __attribute__((ext_vector_type(4)));
typedef float f32x4 __attribute__((ext_vector_type(4)));

#define DIM 1280
#define NHEADS 16
#define HDIM 80
#define MLP 5120
#define NTOK 4096
#define QKV_N 3840

#define GLOAD_LDS16(gp, lp)                                                          \
    __builtin_amdgcn_global_load_lds((const __attribute__((address_space(1))) void*)(gp), \
                                     (__attribute__((address_space(3))) void*)(lp), 16, 0, 0)

// ---------------- fused fp32 -> bf16 conversion of all 4 weight tensors ------
__global__ void cvt_all(const float* __restrict__ s0, const float* __restrict__ s1,
                        const float* __restrict__ s2, const float* __restrict__ s3,
                        bf16_t* __restrict__ d0, bf16_t* __restrict__ d1,
                        bf16_t* __restrict__ d2, bf16_t* __restrict__ d3,
                        int n0, int n1, int n2, int n3) {
    int q0 = n0 >> 2, q1 = n1 >> 2, q2 = n2 >> 2, q3 = n3 >> 2;
    int total = q0 + q1 + q2 + q3;
    for (int i = blockIdx.x * blockDim.x + threadIdx.x; i < total;
         i += gridDim.x * blockDim.x) {
        const float* src;
        bf16_t* dst;
        int j = i;
        if (j < q0) { src = s0; dst = d0; }
        else if ((j -= q0) < q1) { src = s1; dst = d1; }
        else if ((j -= q1) < q2) { src = s2; dst = d2; }
        else { j -= q2; src = s3; dst = d3; }
        float4 v = ((const float4*)src)[j];
        bf16x4 o;
        o[0] = (bf16_t)v.x; o[1] = (bf16_t)v.y; o[2] = (bf16_t)v.z; o[3] = (bf16_t)v.w;
        *(bf16x4*)(dst + j * 4) = o;
    }
}

// ---------------- LayerNorm (fp32 in, bf16 out) ----------------
__global__ __launch_bounds__(256) void ln_kernel(const float* __restrict__ x,
                                                 const float* __restrict__ w,
                                                 const float* __restrict__ b,
                                                 bf16_t* __restrict__ out) {
    int row = blockIdx.x;
    const float* xr = x + (long)row * DIM;
    float v[5];
    float s = 0.f, ss = 0.f;
#pragma unroll
    for (int j = 0; j < 5; j++) {
        v[j] = xr[j * 256 + threadIdx.x];
        s += v[j];
        ss += v[j] * v[j];
    }
#pragma unroll
    for (int off = 32; off > 0; off >>= 1) {
        s += __shfl_xor(s, off, 64);
        ss += __shfl_xor(ss, off, 64);
    }
    __shared__ float red[8];
    int wid = threadIdx.x >> 6;
    if ((threadIdx.x & 63) == 0) { red[wid] = s; red[wid + 4] = ss; }
    __syncthreads();
    s = red[0] + red[1] + red[2] + red[3];
    ss = red[4] + red[5] + red[6] + red[7];
    float mean = s * (1.f / DIM);
    float var = ss * (1.f / DIM) - mean * mean;
    float rstd = rsqrtf(var + 1e-6f);
    bf16_t* orow = out + (long)row * DIM;
#pragma unroll
    for (int j = 0; j < 5; j++) {
        int d = j * 256 + threadIdx.x;
        orow[d] = (bf16_t)((v[j] - mean) * rstd * w[d] + b[d]);
    }
}

// ---------------- prep: fused RoPE + layouts; Q pre-scaled by scale*log2e ----
__global__ __launch_bounds__(256) void prep_kernel(const bf16_t* __restrict__ qkv,
                                                   const float* __restrict__ rot,
                                                   bf16_t* __restrict__ Qd,
                                                   bf16_t* __restrict__ Kd,
                                                   bf16_t* __restrict__ Vt) {
    const float SCL = 0.11180339887498949f * 1.4426950408889634f;  // 1/sqrt(80)*log2(e)
    __shared__ bf16_t tv[64 * 88];
    const int tid = threadIdx.x;
    const int t0 = blockIdx.x * 64;
    const int h = blockIdx.y;

    for (int c = tid; c < 64 * 10; c += 256) {
        int tl = c / 10, a = c % 10;
        bf16x8 v = *(const bf16x8*)(qkv + (long)(t0 + tl) * QKV_N + 2 * DIM + h * HDIM + a * 8);
        *(bf16x8*)(tv + tl * 88 + a * 8) = v;
    }

    for (int c = tid; c < 64 * 10; c += 256) {
        int tl = c / 10, a = c % 10;
        long gq = (long)(t0 + tl) * QKV_N + h * HDIM + a * 4;
        bf16x4 q1 = *(const bf16x4*)(qkv + gq);
        bf16x4 q2 = *(const bf16x4*)(qkv + gq + 40);
        bf16x4 k1 = *(const bf16x4*)(qkv + gq + DIM);
        bf16x4 k2 = *(const bf16x4*)(qkv + gq + DIM + 40);
        float4 rv = *(const float4*)(rot + (long)(t0 + tl) * 40 + a * 4);
        float rr[4] = {rv.x, rv.y, rv.z, rv.w};
        bf16x4 oq1, oq2, ok1, ok2;
#pragma unroll
        for (int j = 0; j < 4; j++) {
            float c_, s_;
            __sincosf(rr[j], &s_, &c_);
            float x1 = (float)q1[j], x2 = (float)q2[j];
            oq1[j] = (bf16_t)((x1 * c_ - x2 * s_) * SCL);
            oq2[j] = (bf16_t)((x2 * c_ + x1 * s_) * SCL);
            x1 = (float)k1[j]; x2 = (float)k2[j];
            ok1[j] = (bf16_t)(x1 * c_ - x2 * s_);
            ok2[j] = (bf16_t)(x2 * c_ + x1 * s_);
        }
        long o = ((long)h * NTOK + t0 + tl) * 96 + a * 4;
        *(bf16x4*)(Qd + o) = oq1;
        *(bf16x4*)(Qd + o + 40) = oq2;
        *(bf16x4*)(Kd + o) = ok1;
        *(bf16x4*)(Kd + o + 40) = ok2;
    }
    {
        bf16x8 z;
#pragma unroll
        for (int j = 0; j < 8; j++) z[j] = (bf16_t)0.f;
        for (int c = tid; c < 64 * 2; c += 256) {
            int tl = c / 2, a = c % 2;
            long o = ((long)h * NTOK + t0 + tl) * 96 + 80 + a * 8;
            *(bf16x8*)(Qd + o) = z;
            *(bf16x8*)(Kd + o) = z;
        }
    }
    __syncthreads();

    for (int c = tid; c < 80 * 8; c += 256) {
        int d = c / 8, tc = c % 8;
        bf16x8 v;
#pragma unroll
        for (int j = 0; j < 8; j++) v[j] = tv[(tc * 8 + j) * 88 + d];
        *(bf16x8*)(Vt + ((long)h * HDIM + d) * NTOK + t0 + tc * 8) = v;
    }
}

// ---------------- GEMM: C[M,N] = A[M,K] * B[N,K]^T (+epilogue) -----------------
// 128x128 tile, 8 waves (2M x 4N), per-wave 64x32 (4x2 frags), BK=32.
// 3 LDS bufs x 16KB = 48KB -> 3 blocks/CU; 8 waves/block -> 16-24 waves/CU
// (vs 12 with 4-wave blocks) for latency absorption. Depth-2 counted pipeline:
// entry vmcnt(2) (tile t's 2 loads landed, t+1's 2 in flight), ONE barrier per
// tile, stage(t+2) after barrier. Compiler-managed lgkm. 64B rows, swizzle
// colb ^= (((row>>1)&3)<<4) both-sides (verified 0 conflicts).
// EPI 0: bf16=acc+bias | 1: f32=res+acc+bias | 2: bf16=qgelu(acc+bias)
template <int EPI>
__global__ __launch_bounds__(512, 4) void gemmS(const bf16_t* __restrict__ A,
                                                const bf16_t* __restrict__ B,
                                                const float* __restrict__ bias,
                                                const float* __restrict__ res,
                                                void* __restrict__ Cv,
                                                int M, int N, int K, int kspl) {
    __shared__ char lds[3 * 16384];  // 48 KB
    const int tid = threadIdx.x;
    const int lane = tid & 63;
    const int l15 = lane & 15;
    const int g = lane >> 4;
    const int wid = tid >> 6;   // 0..7
    const int wr = wid >> 2;    // 0..1 (M)
    const int wc = wid & 3;     // 0..3 (N)

    // XCD-bijective block swizzle (x*y grid size % 8 == 0 for all launches)
    const int nx = gridDim.x;
    const int id = blockIdx.y * nx + blockIdx.x;
    const int cpx = (nx * gridDim.y) >> 3;
    const int sid = (id & 7) * cpx + (id >> 3);
    const int m0 = (sid / nx) * 128;
    const int n0 = (sid % nx) * 128;
    const int k0 = blockIdx.z * kspl;
    const int NT = kspl >> 5;  // K-tiles of 32

    // staging maps: 512 thr x 16B = 8KB/call; call 0 = A[128][32], call 1 = B.
    // per-lane global source pre-swizzled; LDS dest linear (wave-uniform base).
    const int soff = tid * 16;                         // byte offset in 8KB region
    const int srow = soff >> 6;                        // 0..127 (64B rows)
    const int scb = (soff & 63) ^ (((srow >> 1) & 3) << 4);
    const bf16_t* gA = A + (long)(m0 + srow) * K + k0 + (scb >> 1);
    const bf16_t* gB = B + (long)(n0 + srow) * K + k0 + (scb >> 1);
    const int lAo = wid * 1024;           // 8 waves x 1KB = 8KB A region
    const int lBo = 8192 + wid * 1024;    // B region

    f32x4 acc[4][2];
#pragma unroll
    for (int i = 0; i < 4; i++)
#pragma unroll
        for (int j = 0; j < 2; j++) acc[i][j] = (f32x4){0.f, 0.f, 0.f, 0.f};

    auto stage = [&](int buf, int t) {
        char* sb = lds + buf * 16384;
        GLOAD_LDS16(gA + t * 32, sb + lAo);
        GLOAD_LDS16(gB + t * 32, sb + lBo);
    };

    stage(0, 0);
    stage(1, 1);

    int buf = 0;
    for (int t = 0; t < NT; ++t) {
        if (t < NT - 1)
            asm volatile("s_waitcnt vmcnt(2)\n\ts_barrier" ::: "memory");
        else
            asm volatile("s_waitcnt vmcnt(0)\n\ts_barrier" ::: "memory");
        if (t + 2 < NT) stage((buf + 2) % 3, t + 2);

        const char* pA = lds + buf * 16384;
        const char* pB = pA + 8192;
        bf16x8 af[4], bb[2];
#pragma unroll
        for (int m = 0; m < 4; m++) {
            int r = wr * 64 + m * 16 + l15;
            af[m] = *(const bf16x8*)(pA + r * 64 + ((g * 16) ^ (((r >> 1) & 3) << 4)));
        }
#pragma unroll
        for (int n = 0; n < 2; n++) {
            int r = wc * 32 + n * 16 + l15;
            bb[n] = *(const bf16x8*)(pB + r * 64 + ((g * 16) ^ (((r >> 1) & 3) << 4)));
        }
        __builtin_amdgcn_s_setprio(1);
#pragma unroll
        for (int m = 0; m < 4; m++)
#pragma unroll
            for (int n = 0; n < 2; n++)
                acc[m][n] = __builtin_amdgcn_mfma_f32_16x16x32_bf16(af[m], bb[n],
                                                                    acc[m][n], 0, 0, 0);
        __builtin_amdgcn_s_setprio(0);
        buf = (buf + 1) % 3;
    }

    // epilogue: D row = (lane>>4)*4 + rr, col = lane&15
#pragma unroll
    for (int m = 0; m < 4; m++)
#pragma unroll
        for (int n = 0; n < 2; n++) {
            const int col = n0 + wc * 32 + n * 16 + l15;
            const float bv = bias[col];
#pragma unroll
            for (int rr = 0; rr < 4; rr++) {
                const int row = m0 + wr * 64 + m * 16 + g * 4 + rr;
                const long idx = (long)row * N + col;
                float val = acc[m][n][rr] + bv;
                if (EPI == 0) {
                    ((bf16_t*)Cv)[idx] = (bf16_t)val;
                } else if (EPI == 1) {
                    ((float*)Cv)[idx] = res[idx] + val;
                } else {
                    float ge = val / (1.f + __expf(-1.702f * val));
                    ((bf16_t*)Cv)[idx] = (bf16_t)ge;
                }
            }
        }
}

// ---------------- Flash attention v3: no-max softmax (unchanged) ----------------
__global__ __launch_bounds__(256) void attn_kernel(const bf16_t* __restrict__ Qd,
                                                   const bf16_t* __restrict__ Kd,
                                                   const bf16_t* __restrict__ Vt,
                                                   const int* __restrict__ cu,
                                                   int ncu,
                                                   bf16_t* __restrict__ out) {
    __shared__ bf16_t lK[64 * 104];   // [k][d], stride 104
    __shared__ bf16_t lV[96 * 64];    // [d][k], 128B rows + XOR swizzle
    __shared__ bf16_t lP[4 * 16 * 72];

    const int tid = threadIdx.x;
    const int lane = tid & 63;
    const int l15 = lane & 15;
    const int g = lane >> 4;
    const int wid = tid >> 6;
    const int h = blockIdx.y;
    const int q0 = blockIdx.x * 64;

    int sseg = 0;
    for (int j = 1; j < ncu - 1; j++) if (q0 >= cu[j]) sseg = j;
    const int kbeg = cu[sseg], kend = cu[sseg + 1];

    bf16x8 aq[3];
    {
        const bf16_t* qp = Qd + ((long)h * NTOK + q0 + wid * 16 + l15) * 96;
#pragma unroll
        for (int ks = 0; ks < 3; ks++)
            aq[ks] = *(const bf16x8*)(qp + ks * 32 + g * 8);
    }

    for (int c = tid; c < 16 * 8; c += 256) {
        int d = 80 + c / 8, a = c % 8;
        bf16x8 v;
#pragma unroll
        for (int j = 0; j < 8; j++) v[j] = (d == 80) ? (bf16_t)1.f : (bf16_t)0.f;
        *(bf16x8*)((char*)lV + d * 128 + ((a * 16) ^ ((d & 7) << 4))) = v;
    }

    f32x4 o[6];
#pragma unroll
    for (int n = 0; n < 6; n++) o[n] = (f32x4){0.f, 0.f, 0.f, 0.f};

    bf16x8 rK[3], rV[3];
    auto ldK = [&](int kt) {
#pragma unroll
        for (int i = 0; i < 3; i++) {
            int c = tid + i * 256;
            int row = c / 12, c16 = c % 12;
            rK[i] = *(const bf16x8*)(Kd + ((long)h * NTOK + kt + row) * 96 + c16 * 8);
        }
    };
    auto ldV = [&](int kt) {
#pragma unroll
        for (int i = 0; i < 3; i++) {
            int c = tid + i * 256;
            if (c < 640) {
                int d = c / 8, a = c % 8;
                rV[i] = *(const bf16x8*)(Vt + ((long)h * HDIM + d) * NTOK + kt + a * 8);
            }
        }
    };
    auto wrKV = [&]() {
#pragma unroll
        for (int i = 0; i < 3; i++) {
            int c = tid + i * 256;
            int row = c / 12, c16 = c % 12;
            *(bf16x8*)(lK + row * 104 + c16 * 8) = rK[i];
        }
#pragma unroll
        for (int i = 0; i < 3; i++) {
            int c = tid + i * 256;
            if (c < 640) {
                int d = c / 8, a = c % 8;
                *(bf16x8*)((char*)lV + d * 128 + ((a * 16) ^ ((d & 7) << 4))) = rV[i];
            }
        }
    };

    ldK(kbeg); ldV(kbeg);
    wrKV();
    __syncthreads();

    for (int kt = kbeg; kt < kend; kt += 64) {
        const bool more = (kt + 64 < kend);
        if (more) { ldK(kt + 64); ldV(kt + 64); }

        f32x4 s[4];
#pragma unroll
        for (int n = 0; n < 4; n++) s[n] = (f32x4){0.f, 0.f, 0.f, 0.f};
#pragma unroll
        for (int n = 0; n < 4; n++)
#pragma unroll
            for (int ks = 0; ks < 3; ks++) {
                bf16x8 kf = *(const bf16x8*)(lK + (n * 16 + l15) * 104 + ks * 32 + g * 8);
                s[n] = __builtin_amdgcn_mfma_f32_16x16x32_bf16(aq[ks], kf, s[n], 0, 0, 0);
            }

#pragma unroll
        for (int n = 0; n < 4; n++)
#pragma unroll
            for (int r = 0; r < 4; r++)
                lP[wid * 1152 + (g * 4 + r) * 72 + n * 16 + l15] = (bf16_t)exp2f(s[n][r]);

        asm volatile("s_waitcnt lgkmcnt(0)" ::: "memory");
        bf16x8 pa[2];
#pragma unroll
        for (int ks = 0; ks < 2; ks++)
            pa[ks] = *(const bf16x8*)(lP + wid * 1152 + l15 * 72 + ks * 32 + g * 8);
#pragma unroll
        for (int n = 0; n < 6; n++)
#pragma unroll
            for (int ks = 0; ks < 2; ks++) {
                int rv = n * 16 + l15;
                bf16x8 vb = *(const bf16x8*)((char*)lV + rv * 128 +
                                             ((ks * 64 + g * 16) ^ ((rv & 7) << 4)));
                o[n] = __builtin_amdgcn_mfma_f32_16x16x32_bf16(pa[ks], vb, o[n], 0, 0, 0);
            }
        __syncthreads();
        if (more) wrKV();
        __syncthreads();
    }

    float lI[4];
#pragma unroll
    for (int r = 0; r < 4; r++) lI[r] = __shfl(o[5][r], lane & 48, 64);

#pragma unroll
    for (int n = 0; n < 5; n++)
#pragma unroll
        for (int r = 0; r < 4; r++) {
            int row = q0 + wid * 16 + g * 4 + r;
            out[(long)row * DIM + h * HDIM + n * 16 + l15] = (bf16_t)(o[n][r] / lI[r]);
        }
}

// ---------------- launch ----------------
extern "C" void kernel_launch(void* const* d_in, const int* in_sizes, int n_in,
                              void* d_out, int out_size, void* d_ws, size_t ws_size,
                              hipStream_t stream) {
    const float* hidden = (const float*)d_in[0];
    const float* rot    = (const float*)d_in[1];
    const int*   cu     = (const int*)d_in[2];
    const float* n1w    = (const float*)d_in[3];
    const float* n1b    = (const float*)d_in[4];
    const float* n2w    = (const float*)d_in[5];
    const float* n2b    = (const float*)d_in[6];
    const float* qkv_w  = (const float*)d_in[7];
    const float* qkv_b  = (const float*)d_in[8];
    const float* proj_w = (const float*)d_in[9];
    const float* proj_b = (const float*)d_in[10];
    const float* fc1_w  = (const float*)d_in[11];
    const float* fc1_b  = (const float*)d_in[12];
    const float* fc2_w  = (const float*)d_in[13];
    const float* fc2_b  = (const float*)d_in[14];
    float* outp = (float*)d_out;

    char* ws = (char*)d_ws;
    bf16_t* w2   = (bf16_t*)(ws);                  // [0,13.1M)        cvt->FC2
    bf16_t* w1   = (bf16_t*)(ws + 13107200);       // [13.1M,26.2M)    cvt->FC1
    bf16_t* wp   = (bf16_t*)(ws + 26214400);       // [26.2M,29.5M)    cvt->proj
    bf16_t* wq   = (bf16_t*)(ws + 29491200);       // [29.5M,39.3M)    cvt->QKV
    bf16_t* xln  = (bf16_t*)(ws + 39321600);       // [39.3M,49.8M)    LN1->QKV, LN2->FC1
    bf16_t* qkvb = (bf16_t*)(ws + 49807360);       // [49.8M,81.3M)    QKV->prep
    bf16_t* Qd   = (bf16_t*)(ws + 81264640);       // [81.3M,93.8M)    prep->attn
    bf16_t* Kd   = (bf16_t*)(ws + 93847552);       // [93.8M,106.4M)   prep->attn
    bf16_t* Vt   = (bf16_t*)(ws + 106430464);      // [106.4M,116.9M)  prep->attn
    bf16_t* attno= (bf16_t*)(ws + 116916224);      // [116.9M,127.4M)  attn->proj
    bf16_t* act  = (bf16_t*)(ws + 49807360);       // [49.8M,91.75M)   FC1->FC2 (qkvb/Qd dead)
    // h (f32) lives in d_out: proj writes (EPI1), LN2 reads, FC2 (EPI1) accumulates.

    int ncu = in_sizes[2];

    cvt_all<<<2048, 256, 0, stream>>>(fc2_w, fc1_w, proj_w, qkv_w,
                                      w2, w1, wp, wq,
                                      DIM * MLP, MLP * DIM, DIM * DIM, QKV_N * DIM);

    ln_kernel<<<NTOK, 256, 0, stream>>>(hidden, n1w, n1b, xln);
    // QKV: 4096x3840x1280 -> 30x32 = 960 blocks, NT=40
    gemmS<0><<<dim3(QKV_N / 128, NTOK / 128, 1), 512, 0, stream>>>(
        xln, wq, qkv_b, nullptr, qkvb, NTOK, QKV_N, DIM, DIM);
    prep_kernel<<<dim3(NTOK / 64, NHEADS), 256, 0, stream>>>(qkvb, rot, Qd, Kd, Vt);
    attn_kernel<<<dim3(NTOK / 64, NHEADS), 256, 0, stream>>>(Qd, Kd, Vt, cu, ncu, attno);
    // proj: 4096x1280x1280 -> 10x32 = 320 blocks, NT=40, direct h = hidden+acc+bias
    gemmS<1><<<dim3(DIM / 128, NTOK / 128, 1), 512, 0, stream>>>(
        attno, wp, proj_b, hidden, outp, NTOK, DIM, DIM, DIM);
    ln_kernel<<<NTOK, 256, 0, stream>>>(outp, n2w, n2b, xln);
    // FC1: 40x32 = 1280 blocks, NT=40
    gemmS<2><<<dim3(MLP / 128, NTOK / 128, 1), 512, 0, stream>>>(
        xln, w1, fc1_b, nullptr, act, NTOK, MLP, DIM, DIM);
    // FC2: 4096x1280x5120 -> 10x32 = 320 blocks, NT=160, direct out = h+acc+bias
    gemmS<1><<<dim3(DIM / 128, NTOK / 128, 1), 512, 0, stream>>>(
        act, w2, fc2_b, outp, outp, NTOK, DIM, MLP, MLP);
}

// Round 17
// 327.047 us; speedup vs baseline: 2.5244x; 1.0130x over previous
//
#include <hip/hip_runtime.h>
#include <hip/hip_bf16.h>

// Qwen2VL vision block, MI355X gfx950.
// R17: gemmT for QKV/FC1 — BM128 x BN256, 16 waves (1024thr), per-wave 64x32,
//      3x24KB bufs (72KB -> 2 blocks/CU -> 32 waves/CU = MAX occupancy),
//      depth-2 counted vmcnt, one barrier/tile. BN=256 halves A-panel refetch.
//      proj/FC2 (N=1280) stay on gemmS (R16, 320-block grids).

typedef __bf16 bf16_t;
typedef bf16_t bf16x8 __attribute__((ext_vector_type(8)));
typedef bf16_t bf16x4 __attribute__((ext_vector_type(4)));
typedef float f32x4 __attribute__((ext_vector_type(4)));

#define DIM 1280
#define NHEADS 16
#define HDIM 80
#define MLP 5120
#define NTOK 4096
#define QKV_N 3840

#define GLOAD_LDS16(gp, lp)                                                          \
    __builtin_amdgcn_global_load_lds((const __attribute__((address_space(1))) void*)(gp), \
                                     (__attribute__((address_space(3))) void*)(lp), 16, 0, 0)

// ---------------- fused fp32 -> bf16 conversion of all 4 weight tensors ------
__global__ void cvt_all(const float* __restrict__ s0, const float* __restrict__ s1,
                        const float* __restrict__ s2, const float* __restrict__ s3,
                        bf16_t* __restrict__ d0, bf16_t* __restrict__ d1,
                        bf16_t* __restrict__ d2, bf16_t* __restrict__ d3,
                        int n0, int n1, int n2, int n3) {
    int q0 = n0 >> 2, q1 = n1 >> 2, q2 = n2 >> 2, q3 = n3 >> 2;
    int total = q0 + q1 + q2 + q3;
    for (int i = blockIdx.x * blockDim.x + threadIdx.x; i < total;
         i += gridDim.x * blockDim.x) {
        const float* src;
        bf16_t* dst;
        int j = i;
        if (j < q0) { src = s0; dst = d0; }
        else if ((j -= q0) < q1) { src = s1; dst = d1; }
        else if ((j -= q1) < q2) { src = s2; dst = d2; }
        else { j -= q2; src = s3; dst = d3; }
        float4 v = ((const float4*)src)[j];
        bf16x4 o;
        o[0] = (bf16_t)v.x; o[1] = (bf16_t)v.y; o[2] = (bf16_t)v.z; o[3] = (bf16_t)v.w;
        *(bf16x4*)(dst + j * 4) = o;
    }
}

// ---------------- LayerNorm (fp32 in, bf16 out) ----------------
__global__ __launch_bounds__(256) void ln_kernel(const float* __restrict__ x,
                                                 const float* __restrict__ w,
                                                 const float* __restrict__ b,
                                                 bf16_t* __restrict__ out) {
    int row = blockIdx.x;
    const float* xr = x + (long)row * DIM;
    float v[5];
    float s = 0.f, ss = 0.f;
#pragma unroll
    for (int j = 0; j < 5; j++) {
        v[j] = xr[j * 256 + threadIdx.x];
        s += v[j];
        ss += v[j] * v[j];
    }
#pragma unroll
    for (int off = 32; off > 0; off >>= 1) {
        s += __shfl_xor(s, off, 64);
        ss += __shfl_xor(ss, off, 64);
    }
    __shared__ float red[8];
    int wid = threadIdx.x >> 6;
    if ((threadIdx.x & 63) == 0) { red[wid] = s; red[wid + 4] = ss; }
    __syncthreads();
    s = red[0] + red[1] + red[2] + red[3];
    ss = red[4] + red[5] + red[6] + red[7];
    float mean = s * (1.f / DIM);
    float var = ss * (1.f / DIM) - mean * mean;
    float rstd = rsqrtf(var + 1e-6f);
    bf16_t* orow = out + (long)row * DIM;
#pragma unroll
    for (int j = 0; j < 5; j++) {
        int d = j * 256 + threadIdx.x;
        orow[d] = (bf16_t)((v[j] - mean) * rstd * w[d] + b[d]);
    }
}

// ---------------- prep: fused RoPE + layouts; Q pre-scaled by scale*log2e ----
__global__ __launch_bounds__(256) void prep_kernel(const bf16_t* __restrict__ qkv,
                                                   const float* __restrict__ rot,
                                                   bf16_t* __restrict__ Qd,
                                                   bf16_t* __restrict__ Kd,
                                                   bf16_t* __restrict__ Vt) {
    const float SCL = 0.11180339887498949f * 1.4426950408889634f;  // 1/sqrt(80)*log2(e)
    __shared__ bf16_t tv[64 * 88];
    const int tid = threadIdx.x;
    const int t0 = blockIdx.x * 64;
    const int h = blockIdx.y;

    for (int c = tid; c < 64 * 10; c += 256) {
        int tl = c / 10, a = c % 10;
        bf16x8 v = *(const bf16x8*)(qkv + (long)(t0 + tl) * QKV_N + 2 * DIM + h * HDIM + a * 8);
        *(bf16x8*)(tv + tl * 88 + a * 8) = v;
    }

    for (int c = tid; c < 64 * 10; c += 256) {
        int tl = c / 10, a = c % 10;
        long gq = (long)(t0 + tl) * QKV_N + h * HDIM + a * 4;
        bf16x4 q1 = *(const bf16x4*)(qkv + gq);
        bf16x4 q2 = *(const bf16x4*)(qkv + gq + 40);
        bf16x4 k1 = *(const bf16x4*)(qkv + gq + DIM);
        bf16x4 k2 = *(const bf16x4*)(qkv + gq + DIM + 40);
        float4 rv = *(const float4*)(rot + (long)(t0 + tl) * 40 + a * 4);
        float rr[4] = {rv.x, rv.y, rv.z, rv.w};
        bf16x4 oq1, oq2, ok1, ok2;
#pragma unroll
        for (int j = 0; j < 4; j++) {
            float c_, s_;
            __sincosf(rr[j], &s_, &c_);
            float x1 = (float)q1[j], x2 = (float)q2[j];
            oq1[j] = (bf16_t)((x1 * c_ - x2 * s_) * SCL);
            oq2[j] = (bf16_t)((x2 * c_ + x1 * s_) * SCL);
            x1 = (float)k1[j]; x2 = (float)k2[j];
            ok1[j] = (bf16_t)(x1 * c_ - x2 * s_);
            ok2[j] = (bf16_t)(x2 * c_ + x1 * s_);
        }
        long o = ((long)h * NTOK + t0 + tl) * 96 + a * 4;
        *(bf16x4*)(Qd + o) = oq1;
        *(bf16x4*)(Qd + o + 40) = oq2;
        *(bf16x4*)(Kd + o) = ok1;
        *(bf16x4*)(Kd + o + 40) = ok2;
    }
    {
        bf16x8 z;
#pragma unroll
        for (int j = 0; j < 8; j++) z[j] = (bf16_t)0.f;
        for (int c = tid; c < 64 * 2; c += 256) {
            int tl = c / 2, a = c % 2;
            long o = ((long)h * NTOK + t0 + tl) * 96 + 80 + a * 8;
            *(bf16x8*)(Qd + o) = z;
            *(bf16x8*)(Kd + o) = z;
        }
    }
    __syncthreads();

    for (int c = tid; c < 80 * 8; c += 256) {
        int d = c / 8, tc = c % 8;
        bf16x8 v;
#pragma unroll
        for (int j = 0; j < 8; j++) v[j] = tv[(tc * 8 + j) * 88 + d];
        *(bf16x8*)(Vt + ((long)h * HDIM + d) * NTOK + t0 + tc * 8) = v;
    }
}

// ---------------- gemmT: BM128 x BN256, 16 waves, max occupancy --------------
// Per-wave 64x32 (4x2 frags). LDS buf = A[128][32] 8KB @0 + B[256][32] 16KB
// @8192 = 24KB; 3 bufs = 72KB -> 2 blocks/CU x 16 waves = 32 waves/CU (max).
// Staging: call0 (all 16 waves) covers [0,16KB) = A + B rows 0..127;
// call1 (waves 0..7) covers [16KB,24KB) = B rows 128..255. Depth-2 counted
// entry wait: waves<8 vmcnt(2), waves>=8 vmcnt(1) (per-wave counters).
// 64B rows, swizzle colb ^= (((row>>1)&3)<<4) both-sides (0 conflicts).
// EPI 0: bf16=acc+bias | 2: bf16=qgelu(acc+bias)
template <int EPI>
__global__ __launch_bounds__(1024, 2) void gemmT(const bf16_t* __restrict__ A,
                                                 const bf16_t* __restrict__ B,
                                                 const float* __restrict__ bias,
                                                 void* __restrict__ Cv,
                                                 int M, int N, int K) {
    __shared__ char lds[3 * 24576];  // 72 KB
    const int tid = threadIdx.x;
    const int lane = tid & 63;
    const int l15 = lane & 15;
    const int g = lane >> 4;
    const int wid = tid >> 6;   // 0..15
    const int wr = wid >> 3;    // 0..1 (M)
    const int wc = wid & 7;     // 0..7 (N)

    // XCD-bijective block swizzle (grid x*y % 8 == 0)
    const int nx = gridDim.x;
    const int id = blockIdx.y * nx + blockIdx.x;
    const int cpx = (nx * gridDim.y) >> 3;
    const int sid = (id & 7) * cpx + (id >> 3);
    const int m0 = (sid / nx) * 128;
    const int n0 = (sid % nx) * 256;
    const int NT = K >> 5;  // K-tiles of 32

    // staging sources (pre-swizzled global col; linear LDS dest)
    const bf16_t* g0;
    {
        int off = tid * 16;  // [0,16384)
        if (off < 8192) {
            int row = off >> 6;
            int cb = (off & 63) ^ (((row >> 1) & 3) << 4);
            g0 = A + (long)(m0 + row) * K + (cb >> 1);
        } else {
            int b = off - 8192;
            int row = b >> 6;  // B row 0..127
            int cb = (b & 63) ^ (((row >> 1) & 3) << 4);
            g0 = B + (long)(n0 + row) * K + (cb >> 1);
        }
    }
    const bf16_t* g1;
    {
        int b = (tid & 511) * 16;       // [0,8192) for waves 0..7
        int row = 128 + (b >> 6);       // B row 128..255
        int cb = (b & 63) ^ (((row >> 1) & 3) << 4);
        g1 = B + (long)(n0 + row) * K + (cb >> 1);
    }
    const int l0 = wid * 1024;          // linear dest in [0,16KB)
    const int l1 = 16384 + wid * 1024;  // dest in [16KB,24KB) (waves 0..7)

    f32x4 acc[4][2];
#pragma unroll
    for (int i = 0; i < 4; i++)
#pragma unroll
        for (int j = 0; j < 2; j++) acc[i][j] = (f32x4){0.f, 0.f, 0.f, 0.f};

    auto stage = [&](int buf, int t) {
        char* sb = lds + buf * 24576;
        GLOAD_LDS16(g0 + t * 32, sb + l0);
        if (wid < 8) GLOAD_LDS16(g1 + t * 32, sb + l1);
    };

    stage(0, 0);
    stage(1, 1);

    int buf = 0;
    for (int t = 0; t < NT; ++t) {
        if (t < NT - 1) {
            if (wid < 8) asm volatile("s_waitcnt vmcnt(2)" ::: "memory");
            else         asm volatile("s_waitcnt vmcnt(1)" ::: "memory");
        } else {
            asm volatile("s_waitcnt vmcnt(0)" ::: "memory");
        }
        asm volatile("s_barrier" ::: "memory");
        if (t + 2 < NT) stage((buf + 2) % 3, t + 2);

        const char* pA = lds + buf * 24576;
        const char* pB = pA + 8192;
        bf16x8 af[4], bb[2];
#pragma unroll
        for (int m = 0; m < 4; m++) {
            int r = wr * 64 + m * 16 + l15;
            af[m] = *(const bf16x8*)(pA + r * 64 + ((g * 16) ^ (((r >> 1) & 3) << 4)));
        }
#pragma unroll
        for (int n = 0; n < 2; n++) {
            int r = wc * 32 + n * 16 + l15;
            bb[n] = *(const bf16x8*)(pB + r * 64 + ((g * 16) ^ (((r >> 1) & 3) << 4)));
        }
        __builtin_amdgcn_s_setprio(1);
#pragma unroll
        for (int m = 0; m < 4; m++)
#pragma unroll
            for (int n = 0; n < 2; n++)
                acc[m][n] = __builtin_amdgcn_mfma_f32_16x16x32_bf16(af[m], bb[n],
                                                                    acc[m][n], 0, 0, 0);
        __builtin_amdgcn_s_setprio(0);
        buf = (buf + 1) % 3;
    }

    // epilogue: D row = (lane>>4)*4 + rr, col = lane&15
#pragma unroll
    for (int m = 0; m < 4; m++)
#pragma unroll
        for (int n = 0; n < 2; n++) {
            const int col = n0 + wc * 32 + n * 16 + l15;
            const float bv = bias[col];
#pragma unroll
            for (int rr = 0; rr < 4; rr++) {
                const int row = m0 + wr * 64 + m * 16 + g * 4 + rr;
                const long idx = (long)row * N + col;
                float val = acc[m][n][rr] + bv;
                if (EPI == 0) {
                    ((bf16_t*)Cv)[idx] = (bf16_t)val;
                } else {
                    float ge = val / (1.f + __expf(-1.702f * val));
                    ((bf16_t*)Cv)[idx] = (bf16_t)ge;
                }
            }
        }
}

// ---------------- gemmS (R16, unchanged): proj / FC2 -------------------------
template <int EPI>
__global__ __launch_bounds__(512, 4) void gemmS(const bf16_t* __restrict__ A,
                                                const bf16_t* __restrict__ B,
                                                const float* __restrict__ bias,
                                                const float* __restrict__ res,
                                                void* __restrict__ Cv,
                                                int M, int N, int K, int kspl) {
    __shared__ char lds[3 * 16384];  // 48 KB
    const int tid = threadIdx.x;
    const int lane = tid & 63;
    const int l15 = lane & 15;
    const int g = lane >> 4;
    const int wid = tid >> 6;   // 0..7
    const int wr = wid >> 2;    // 0..1 (M)
    const int wc = wid & 3;     // 0..3 (N)

    const int nx = gridDim.x;
    const int id = blockIdx.y * nx + blockIdx.x;
    const int cpx = (nx * gridDim.y) >> 3;
    const int sid = (id & 7) * cpx + (id >> 3);
    const int m0 = (sid / nx) * 128;
    const int n0 = (sid % nx) * 128;
    const int k0 = blockIdx.z * kspl;
    const int NT = kspl >> 5;

    const int soff = tid * 16;
    const int srow = soff >> 6;
    const int scb = (soff & 63) ^ (((srow >> 1) & 3) << 4);
    const bf16_t* gA = A + (long)(m0 + srow) * K + k0 + (scb >> 1);
    const bf16_t* gB = B + (long)(n0 + srow) * K + k0 + (scb >> 1);
    const int lAo = wid * 1024;
    const int lBo = 8192 + wid * 1024;

    f32x4 acc[4][2];
#pragma unroll
    for (int i = 0; i < 4; i++)
#pragma unroll
        for (int j = 0; j < 2; j++) acc[i][j] = (f32x4){0.f, 0.f, 0.f, 0.f};

    auto stage = [&](int buf, int t) {
        char* sb = lds + buf * 16384;
        GLOAD_LDS16(gA + t * 32, sb + lAo);
        GLOAD_LDS16(gB + t * 32, sb + lBo);
    };

    stage(0, 0);
    stage(1, 1);

    int buf = 0;
    for (int t = 0; t < NT; ++t) {
        if (t < NT - 1)
            asm volatile("s_waitcnt vmcnt(2)\n\ts_barrier" ::: "memory");
        else
            asm volatile("s_waitcnt vmcnt(0)\n\ts_barrier" ::: "memory");
        if (t + 2 < NT) stage((buf + 2) % 3, t + 2);

        const char* pA = lds + buf * 16384;
        const char* pB = pA + 8192;
        bf16x8 af[4], bb[2];
#pragma unroll
        for (int m = 0; m < 4; m++) {
            int r = wr * 64 + m * 16 + l15;
            af[m] = *(const bf16x8*)(pA + r * 64 + ((g * 16) ^ (((r >> 1) & 3) << 4)));
        }
#pragma unroll
        for (int n = 0; n < 2; n++) {
            int r = wc * 32 + n * 16 + l15;
            bb[n] = *(const bf16x8*)(pB + r * 64 + ((g * 16) ^ (((r >> 1) & 3) << 4)));
        }
        __builtin_amdgcn_s_setprio(1);
#pragma unroll
        for (int m = 0; m < 4; m++)
#pragma unroll
            for (int n = 0; n < 2; n++)
                acc[m][n] = __builtin_amdgcn_mfma_f32_16x16x32_bf16(af[m], bb[n],
                                                                    acc[m][n], 0, 0, 0);
        __builtin_amdgcn_s_setprio(0);
        buf = (buf + 1) % 3;
    }

#pragma unroll
    for (int m = 0; m < 4; m++)
#pragma unroll
        for (int n = 0; n < 2; n++) {
            const int col = n0 + wc * 32 + n * 16 + l15;
            const float bv = bias[col];
#pragma unroll
            for (int rr = 0; rr < 4; rr++) {
                const int row = m0 + wr * 64 + m * 16 + g * 4 + rr;
                const long idx = (long)row * N + col;
                float val = acc[m][n][rr] + bv;
                if (EPI == 0) {
                    ((bf16_t*)Cv)[idx] = (bf16_t)val;
                } else if (EPI == 1) {
                    ((float*)Cv)[idx] = res[idx] + val;
                } else {
                    float ge = val / (1.f + __expf(-1.702f * val));
                    ((bf16_t*)Cv)[idx] = (bf16_t)ge;
                }
            }
        }
}

// ---------------- Flash attention v3: no-max softmax (unchanged) ----------------
__global__ __launch_bounds__(256) void attn_kernel(const bf16_t* __restrict__ Qd,
                                                   const bf16_t* __restrict__ Kd,
                                                   const bf16_t* __restrict__ Vt,
                                                   const int* __restrict__ cu,
                                                   int ncu,
                                                   bf16_t* __restrict__ out) {
    __shared__ bf16_t lK[64 * 104];
    __shared__ bf16_t lV[96 * 64];
    __shared__ bf16_t lP[4 * 16 * 72];

    const int tid = threadIdx.x;
    const int lane = tid & 63;
    const int l15 = lane & 15;
    const int g = lane >> 4;
    const int wid = tid >> 6;
    const int h = blockIdx.y;
    const int q0 = blockIdx.x * 64;

    int sseg = 0;
    for (int j = 1; j < ncu - 1; j++) if (q0 >= cu[j]) sseg = j;
    const int kbeg = cu[sseg], kend = cu[sseg + 1];

    bf16x8 aq[3];
    {
        const bf16_t* qp = Qd + ((long)h * NTOK + q0 + wid * 16 + l15) * 96;
#pragma unroll
        for (int ks = 0; ks < 3; ks++)
            aq[ks] = *(const bf16x8*)(qp + ks * 32 + g * 8);
    }

    for (int c = tid; c < 16 * 8; c += 256) {
        int d = 80 + c / 8, a = c % 8;
        bf16x8 v;
#pragma unroll
        for (int j = 0; j < 8; j++) v[j] = (d == 80) ? (bf16_t)1.f : (bf16_t)0.f;
        *(bf16x8*)((char*)lV + d * 128 + ((a * 16) ^ ((d & 7) << 4))) = v;
    }

    f32x4 o[6];
#pragma unroll
    for (int n = 0; n < 6; n++) o[n] = (f32x4){0.f, 0.f, 0.f, 0.f};

    bf16x8 rK[3], rV[3];
    auto ldK = [&](int kt) {
#pragma unroll
        for (int i = 0; i < 3; i++) {
            int c = tid + i * 256;
            int row = c / 12, c16 = c % 12;
            rK[i] = *(const bf16x8*)(Kd + ((long)h * NTOK + kt + row) * 96 + c16 * 8);
        }
    };
    auto ldV = [&](int kt) {
#pragma unroll
        for (int i = 0; i < 3; i++) {
            int c = tid + i * 256;
            if (c < 640) {
                int d = c / 8, a = c % 8;
                rV[i] = *(const bf16x8*)(Vt + ((long)h * HDIM + d) * NTOK + kt + a * 8);
            }
        }
    };
    auto wrKV = [&]() {
#pragma unroll
        for (int i = 0; i < 3; i++) {
            int c = tid + i * 256;
            int row = c / 12, c16 = c % 12;
            *(bf16x8*)(lK + row * 104 + c16 * 8) = rK[i];
        }
#pragma unroll
        for (int i = 0; i < 3; i++) {
            int c = tid + i * 256;
            if (c < 640) {
                int d = c / 8, a = c % 8;
                *(bf16x8*)((char*)lV + d * 128 + ((a * 16) ^ ((d & 7) << 4))) = rV[i];
            }
        }
    };

    ldK(kbeg); ldV(kbeg);
    wrKV();
    __syncthreads();

    for (int kt = kbeg; kt < kend; kt += 64) {
        const bool more = (kt + 64 < kend);
        if (more) { ldK(kt + 64); ldV(kt + 64); }

        f32x4 s[4];
#pragma unroll
        for (int n = 0; n < 4; n++) s[n] = (f32x4){0.f, 0.f, 0.f, 0.f};
#pragma unroll
        for (int n = 0; n < 4; n++)
#pragma unroll
            for (int ks = 0; ks < 3; ks++) {
                bf16x8 kf = *(const bf16x8*)(lK + (n * 16 + l15) * 104 + ks * 32 + g * 8);
                s[n] = __builtin_amdgcn_mfma_f32_16x16x32_bf16(aq[ks], kf, s[n], 0, 0, 0);
            }

#pragma unroll
        for (int n = 0; n < 4; n++)
#pragma unroll
            for (int r = 0; r < 4; r++)
                lP[wid * 1152 + (g * 4 + r) * 72 + n * 16 + l15] = (bf16_t)exp2f(s[n][r]);

        asm volatile("s_waitcnt lgkmcnt(0)" ::: "memory");
        bf16x8 pa[2];
#pragma unroll
        for (int ks = 0; ks < 2; ks++)
            pa[ks] = *(const bf16x8*)(lP + wid * 1152 + l15 * 72 + ks * 32 + g * 8);
#pragma unroll
        for (int n = 0; n < 6; n++)
#pragma unroll
            for (int ks = 0; ks < 2; ks++) {
                int rv = n * 16 + l15;
                bf16x8 vb = *(const bf16x8*)((char*)lV + rv * 128 +
                                             ((ks * 64 + g * 16) ^ ((rv & 7) << 4)));
                o[n] = __builtin_amdgcn_mfma_f32_16x16x32_bf16(pa[ks], vb, o[n], 0, 0, 0);
            }
        __syncthreads();
        if (more) wrKV();
        __syncthreads();
    }

    float lI[4];
#pragma unroll
    for (int r = 0; r < 4; r++) lI[r] = __shfl(o[5][r], lane & 48, 64);

#pragma unroll
    for (int n = 0; n < 5; n++)
#pragma unroll
        for (int r = 0; r < 4; r++) {
            int row = q0 + wid * 16 + g * 4 + r;
            out[(long)row * DIM + h * HDIM + n * 16 + l15] = (bf16_t)(o[n][r] / lI[r]);
        }
}

// ---------------- launch ----------------
extern "C" void kernel_launch(void* const* d_in, const int* in_sizes, int n_in,
                              void* d_out, int out_size, void* d_ws, size_t ws_size,
                              hipStream_t stream) {
    const float* hidden = (const float*)d_in[0];
    const float* rot    = (const float*)d_in[1];
    const int*   cu     = (const int*)d_in[2];
    const float* n1w    = (const float*)d_in[3];
    const float* n1b    = (const float*)d_in[4];
    const float* n2w    = (const float*)d_in[5];
    const float* n2b    = (const float*)d_in[6];
    const float* qkv_w  = (const float*)d_in[7];
    const float* qkv_b  = (const float*)d_in[8];
    const float* proj_w = (const float*)d_in[9];
    const float* proj_b = (const float*)d_in[10];
    const float* fc1_w  = (const float*)d_in[11];
    const float* fc1_b  = (const float*)d_in[12];
    const float* fc2_w  = (const float*)d_in[13];
    const float* fc2_b  = (const float*)d_in[14];
    float* outp = (float*)d_out;

    char* ws = (char*)d_ws;
    bf16_t* w2   = (bf16_t*)(ws);                  // [0,13.1M)        cvt->FC2
    bf16_t* w1   = (bf16_t*)(ws + 13107200);       // [13.1M,26.2M)    cvt->FC1
    bf16_t* wp   = (bf16_t*)(ws + 26214400);       // [26.2M,29.5M)    cvt->proj
    bf16_t* wq   = (bf16_t*)(ws + 29491200);       // [29.5M,39.3M)    cvt->QKV
    bf16_t* xln  = (bf16_t*)(ws + 39321600);       // [39.3M,49.8M)    LN1->QKV, LN2->FC1
    bf16_t* qkvb = (bf16_t*)(ws + 49807360);       // [49.8M,81.3M)    QKV->prep
    bf16_t* Qd   = (bf16_t*)(ws + 81264640);       // [81.3M,93.8M)    prep->attn
    bf16_t* Kd   = (bf16_t*)(ws + 93847552);       // [93.8M,106.4M)   prep->attn
    bf16_t* Vt   = (bf16_t*)(ws + 106430464);      // [106.4M,116.9M)  prep->attn
    bf16_t* attno= (bf16_t*)(ws + 116916224);      // [116.9M,127.4M)  attn->proj
    bf16_t* act  = (bf16_t*)(ws + 49807360);       // [49.8M,91.75M)   FC1->FC2 (qkvb/Qd dead)
    // h (f32) lives in d_out: proj writes (EPI1), LN2 reads, FC2 (EPI1) accumulates.

    int ncu = in_sizes[2];

    cvt_all<<<2048, 256, 0, stream>>>(fc2_w, fc1_w, proj_w, qkv_w,
                                      w2, w1, wp, wq,
                                      DIM * MLP, MLP * DIM, DIM * DIM, QKV_N * DIM);

    ln_kernel<<<NTOK, 256, 0, stream>>>(hidden, n1w, n1b, xln);
    // QKV: 4096x3840x1280 -> 15x32 = 480 blocks (BN=256), NT=40
    gemmT<0><<<dim3(QKV_N / 256, NTOK / 128, 1), 1024, 0, stream>>>(
        xln, wq, qkv_b, qkvb, NTOK, QKV_N, DIM);
    prep_kernel<<<dim3(NTOK / 64, NHEADS), 256, 0, stream>>>(qkvb, rot, Qd, Kd, Vt);
    attn_kernel<<<dim3(NTOK / 64, NHEADS), 256, 0, stream>>>(Qd, Kd, Vt, cu, ncu, attno);
    // proj: 4096x1280x1280 -> 10x32 = 320 blocks, NT=40, direct h = hidden+acc+bias
    gemmS<1><<<dim3(DIM / 128, NTOK / 128, 1), 512, 0, stream>>>(
        attno, wp, proj_b, hidden, outp, NTOK, DIM, DIM, DIM);
    ln_kernel<<<NTOK, 256, 0, stream>>>(outp, n2w, n2b, xln);
    // FC1: 4096x5120x1280 -> 20x32 = 640 blocks (BN=256), NT=40
    gemmT<2><<<dim3(MLP / 256, NTOK / 128, 1), 1024, 0, stream>>>(
        xln, w1, fc1_b, act, NTOK, MLP, DIM);
    // FC2: 4096x1280x5120 -> 10x32 = 320 blocks, NT=160, direct out = h+acc+bias
    gemmS<1><<<dim3(DIM / 128, NTOK / 128, 1), 512, 0, stream>>>(
        act, w2, fc2_b, outp, outp, NTOK, DIM, MLP, MLP);
}

// Round 18
// 312.986 us; speedup vs baseline: 2.6378x; 1.0449x over previous
//
#include <hip/hip_runtime.h>
#include <hip/hip_bf16.h>

// Qwen2VL vision block, MI355X gfx950.
// R18: gemmU for QKV/FC1 — per-wave 64x64 (16 MFMA : 8 b128 reads, 2x better
//      MFMA:LDS-port ratio -> ~44% ceiling) x 8 waves = 128x256 tile, BK=32,
//      3x24KB bufs (72KB -> 2 blocks/CU, 16 waves/CU), depth-2 counted
//      vmcnt(3), one barrier/tile. proj/FC2 stay on gemmS (R16).

typedef __bf16 bf16_t;
typedef bf16_t bf16x8 __attribute__((ext_vector_type(8)));
typedef bf16_t bf16x4 __attribute__((ext_vector_type(4)));
typedef float f32x4 __attribute__((ext_vector_type(4)));

#define DIM 1280
#define NHEADS 16
#define HDIM 80
#define MLP 5120
#define NTOK 4096
#define QKV_N 3840

#define GLOAD_LDS16(gp, lp)                                                          \
    __builtin_amdgcn_global_load_lds((const __attribute__((address_space(1))) void*)(gp), \
                                     (__attribute__((address_space(3))) void*)(lp), 16, 0, 0)

// ---------------- fused fp32 -> bf16 conversion of all 4 weight tensors ------
__global__ void cvt_all(const float* __restrict__ s0, const float* __restrict__ s1,
                        const float* __restrict__ s2, const float* __restrict__ s3,
                        bf16_t* __restrict__ d0, bf16_t* __restrict__ d1,
                        bf16_t* __restrict__ d2, bf16_t* __restrict__ d3,
                        int n0, int n1, int n2, int n3) {
    int q0 = n0 >> 2, q1 = n1 >> 2, q2 = n2 >> 2, q3 = n3 >> 2;
    int total = q0 + q1 + q2 + q3;
    for (int i = blockIdx.x * blockDim.x + threadIdx.x; i < total;
         i += gridDim.x * blockDim.x) {
        const float* src;
        bf16_t* dst;
        int j = i;
        if (j < q0) { src = s0; dst = d0; }
        else if ((j -= q0) < q1) { src = s1; dst = d1; }
        else if ((j -= q1) < q2) { src = s2; dst = d2; }
        else { j -= q2; src = s3; dst = d3; }
        float4 v = ((const float4*)src)[j];
        bf16x4 o;
        o[0] = (bf16_t)v.x; o[1] = (bf16_t)v.y; o[2] = (bf16_t)v.z; o[3] = (bf16_t)v.w;
        *(bf16x4*)(dst + j * 4) = o;
    }
}

// ---------------- LayerNorm (fp32 in, bf16 out) ----------------
__global__ __launch_bounds__(256) void ln_kernel(const float* __restrict__ x,
                                                 const float* __restrict__ w,
                                                 const float* __restrict__ b,
                                                 bf16_t* __restrict__ out) {
    int row = blockIdx.x;
    const float* xr = x + (long)row * DIM;
    float v[5];
    float s = 0.f, ss = 0.f;
#pragma unroll
    for (int j = 0; j < 5; j++) {
        v[j] = xr[j * 256 + threadIdx.x];
        s += v[j];
        ss += v[j] * v[j];
    }
#pragma unroll
    for (int off = 32; off > 0; off >>= 1) {
        s += __shfl_xor(s, off, 64);
        ss += __shfl_xor(ss, off, 64);
    }
    __shared__ float red[8];
    int wid = threadIdx.x >> 6;
    if ((threadIdx.x & 63) == 0) { red[wid] = s; red[wid + 4] = ss; }
    __syncthreads();
    s = red[0] + red[1] + red[2] + red[3];
    ss = red[4] + red[5] + red[6] + red[7];
    float mean = s * (1.f / DIM);
    float var = ss * (1.f / DIM) - mean * mean;
    float rstd = rsqrtf(var + 1e-6f);
    bf16_t* orow = out + (long)row * DIM;
#pragma unroll
    for (int j = 0; j < 5; j++) {
        int d = j * 256 + threadIdx.x;
        orow[d] = (bf16_t)((v[j] - mean) * rstd * w[d] + b[d]);
    }
}

// ---------------- prep: fused RoPE + layouts; Q pre-scaled by scale*log2e ----
__global__ __launch_bounds__(256) void prep_kernel(const bf16_t* __restrict__ qkv,
                                                   const float* __restrict__ rot,
                                                   bf16_t* __restrict__ Qd,
                                                   bf16_t* __restrict__ Kd,
                                                   bf16_t* __restrict__ Vt) {
    const float SCL = 0.11180339887498949f * 1.4426950408889634f;  // 1/sqrt(80)*log2(e)
    __shared__ bf16_t tv[64 * 88];
    const int tid = threadIdx.x;
    const int t0 = blockIdx.x * 64;
    const int h = blockIdx.y;

    for (int c = tid; c < 64 * 10; c += 256) {
        int tl = c / 10, a = c % 10;
        bf16x8 v = *(const bf16x8*)(qkv + (long)(t0 + tl) * QKV_N + 2 * DIM + h * HDIM + a * 8);
        *(bf16x8*)(tv + tl * 88 + a * 8) = v;
    }

    for (int c = tid; c < 64 * 10; c += 256) {
        int tl = c / 10, a = c % 10;
        long gq = (long)(t0 + tl) * QKV_N + h * HDIM + a * 4;
        bf16x4 q1 = *(const bf16x4*)(qkv + gq);
        bf16x4 q2 = *(const bf16x4*)(qkv + gq + 40);
        bf16x4 k1 = *(const bf16x4*)(qkv + gq + DIM);
        bf16x4 k2 = *(const bf16x4*)(qkv + gq + DIM + 40);
        float4 rv = *(const float4*)(rot + (long)(t0 + tl) * 40 + a * 4);
        float rr[4] = {rv.x, rv.y, rv.z, rv.w};
        bf16x4 oq1, oq2, ok1, ok2;
#pragma unroll
        for (int j = 0; j < 4; j++) {
            float c_, s_;
            __sincosf(rr[j], &s_, &c_);
            float x1 = (float)q1[j], x2 = (float)q2[j];
            oq1[j] = (bf16_t)((x1 * c_ - x2 * s_) * SCL);
            oq2[j] = (bf16_t)((x2 * c_ + x1 * s_) * SCL);
            x1 = (float)k1[j]; x2 = (float)k2[j];
            ok1[j] = (bf16_t)(x1 * c_ - x2 * s_);
            ok2[j] = (bf16_t)(x2 * c_ + x1 * s_);
        }
        long o = ((long)h * NTOK + t0 + tl) * 96 + a * 4;
        *(bf16x4*)(Qd + o) = oq1;
        *(bf16x4*)(Qd + o + 40) = oq2;
        *(bf16x4*)(Kd + o) = ok1;
        *(bf16x4*)(Kd + o + 40) = ok2;
    }
    {
        bf16x8 z;
#pragma unroll
        for (int j = 0; j < 8; j++) z[j] = (bf16_t)0.f;
        for (int c = tid; c < 64 * 2; c += 256) {
            int tl = c / 2, a = c % 2;
            long o = ((long)h * NTOK + t0 + tl) * 96 + 80 + a * 8;
            *(bf16x8*)(Qd + o) = z;
            *(bf16x8*)(Kd + o) = z;
        }
    }
    __syncthreads();

    for (int c = tid; c < 80 * 8; c += 256) {
        int d = c / 8, tc = c % 8;
        bf16x8 v;
#pragma unroll
        for (int j = 0; j < 8; j++) v[j] = tv[(tc * 8 + j) * 88 + d];
        *(bf16x8*)(Vt + ((long)h * HDIM + d) * NTOK + t0 + tc * 8) = v;
    }
}

// ---------------- gemmU: 128(M) x 256(N), 8 waves, per-wave 64x64 ------------
// 16 MFMA : 8 b128 reads per wave per K-tile (BK=32). LDS buf = A[128][32] 8KB
// + B[256][32] 16KB = 24KB; 3 bufs = 72KB -> 2 blocks/CU -> 16 waves/CU.
// Depth-2 counted pipeline: 3 stage-loads/tile, entry vmcnt(3), ONE barrier,
// stage(t+2) after barrier. 64B rows, swizzle colb ^= (((row>>1)&3)<<4).
// EPI 0: bf16=acc+bias | 2: bf16=qgelu(acc+bias)
template <int EPI>
__global__ __launch_bounds__(512, 2) void gemmU(const bf16_t* __restrict__ A,
                                                const bf16_t* __restrict__ B,
                                                const float* __restrict__ bias,
                                                void* __restrict__ Cv,
                                                int M, int N, int K) {
    __shared__ char lds[3 * 24576];  // 72 KB
    const int tid = threadIdx.x;
    const int lane = tid & 63;
    const int l15 = lane & 15;
    const int g = lane >> 4;
    const int wid = tid >> 6;   // 0..7
    const int wr = wid >> 2;    // 0..1 (M)
    const int wc = wid & 3;     // 0..3 (N)

    // XCD-bijective block swizzle (grid x*y % 8 == 0)
    const int nx = gridDim.x;
    const int id = blockIdx.y * nx + blockIdx.x;
    const int cpx = (nx * gridDim.y) >> 3;
    const int sid = (id & 7) * cpx + (id >> 3);
    const int m0 = (sid / nx) * 128;
    const int n0 = (sid % nx) * 256;
    const int NT = K >> 5;  // K-tiles of 32

    // staging sources: 3 calls x 8KB (512 thr x 16B). call0 = A[128][32];
    // call1 = B rows 0..127; call2 = B rows 128..255. Pre-swizzled global col.
    const int soff = tid * 16;                      // [0,8192)
    const int srow = soff >> 6;                     // 0..127
    const int scb = (soff & 63) ^ (((srow >> 1) & 3) << 4);
    const bf16_t* g0 = A + (long)(m0 + srow) * K + (scb >> 1);
    const bf16_t* g1 = B + (long)(n0 + srow) * K + (scb >> 1);
    const int srow2 = 128 + srow;
    const int scb2 = (soff & 63) ^ (((srow2 >> 1) & 3) << 4);
    const bf16_t* g2 = B + (long)(n0 + srow2) * K + (scb2 >> 1);
    const int l0 = wid * 1024;            // A region [0,8K)
    const int l1 = 8192 + wid * 1024;     // B rows 0..127 [8K,16K)
    const int l2 = 16384 + wid * 1024;    // B rows 128..255 [16K,24K)

    f32x4 acc[4][4];
#pragma unroll
    for (int i = 0; i < 4; i++)
#pragma unroll
        for (int j = 0; j < 4; j++) acc[i][j] = (f32x4){0.f, 0.f, 0.f, 0.f};

    auto stage = [&](int buf, int t) {
        char* sb = lds + buf * 24576;
        GLOAD_LDS16(g0 + t * 32, sb + l0);
        GLOAD_LDS16(g1 + t * 32, sb + l1);
        GLOAD_LDS16(g2 + t * 32, sb + l2);
    };

    stage(0, 0);
    stage(1, 1);

    int buf = 0;
    for (int t = 0; t < NT; ++t) {
        if (t < NT - 1)
            asm volatile("s_waitcnt vmcnt(3)\n\ts_barrier" ::: "memory");
        else
            asm volatile("s_waitcnt vmcnt(0)\n\ts_barrier" ::: "memory");
        if (t + 2 < NT) stage((buf + 2) % 3, t + 2);

        const char* pA = lds + buf * 24576;
        const char* pB = pA + 8192;
        bf16x8 af[4], bb[4];
#pragma unroll
        for (int m = 0; m < 4; m++) {
            int r = wr * 64 + m * 16 + l15;
            af[m] = *(const bf16x8*)(pA + r * 64 + ((g * 16) ^ (((r >> 1) & 3) << 4)));
        }
#pragma unroll
        for (int n = 0; n < 4; n++) {
            int r = wc * 64 + n * 16 + l15;
            bb[n] = *(const bf16x8*)(pB + r * 64 + ((g * 16) ^ (((r >> 1) & 3) << 4)));
        }
        __builtin_amdgcn_s_setprio(1);
#pragma unroll
        for (int m = 0; m < 4; m++)
#pragma unroll
            for (int n = 0; n < 4; n++)
                acc[m][n] = __builtin_amdgcn_mfma_f32_16x16x32_bf16(af[m], bb[n],
                                                                    acc[m][n], 0, 0, 0);
        __builtin_amdgcn_s_setprio(0);
        buf = (buf + 1) % 3;
    }

    // epilogue: D row = (lane>>4)*4 + rr, col = lane&15
#pragma unroll
    for (int m = 0; m < 4; m++)
#pragma unroll
        for (int n = 0; n < 4; n++) {
            const int col = n0 + wc * 64 + n * 16 + l15;
            const float bv = bias[col];
#pragma unroll
            for (int rr = 0; rr < 4; rr++) {
                const int row = m0 + wr * 64 + m * 16 + g * 4 + rr;
                const long idx = (long)row * N + col;
                float val = acc[m][n][rr] + bv;
                if (EPI == 0) {
                    ((bf16_t*)Cv)[idx] = (bf16_t)val;
                } else {
                    float ge = val / (1.f + __expf(-1.702f * val));
                    ((bf16_t*)Cv)[idx] = (bf16_t)ge;
                }
            }
        }
}

// ---------------- gemmS (R16, unchanged): proj / FC2 -------------------------
template <int EPI>
__global__ __launch_bounds__(512, 4) void gemmS(const bf16_t* __restrict__ A,
                                                const bf16_t* __restrict__ B,
                                                const float* __restrict__ bias,
                                                const float* __restrict__ res,
                                                void* __restrict__ Cv,
                                                int M, int N, int K, int kspl) {
    __shared__ char lds[3 * 16384];  // 48 KB
    const int tid = threadIdx.x;
    const int lane = tid & 63;
    const int l15 = lane & 15;
    const int g = lane >> 4;
    const int wid = tid >> 6;   // 0..7
    const int wr = wid >> 2;    // 0..1 (M)
    const int wc = wid & 3;     // 0..3 (N)

    const int nx = gridDim.x;
    const int id = blockIdx.y * nx + blockIdx.x;
    const int cpx = (nx * gridDim.y) >> 3;
    const int sid = (id & 7) * cpx + (id >> 3);
    const int m0 = (sid / nx) * 128;
    const int n0 = (sid % nx) * 128;
    const int k0 = blockIdx.z * kspl;
    const int NT = kspl >> 5;

    const int soff = tid * 16;
    const int srow = soff >> 6;
    const int scb = (soff & 63) ^ (((srow >> 1) & 3) << 4);
    const bf16_t* gA = A + (long)(m0 + srow) * K + k0 + (scb >> 1);
    const bf16_t* gB = B + (long)(n0 + srow) * K + k0 + (scb >> 1);
    const int lAo = wid * 1024;
    const int lBo = 8192 + wid * 1024;

    f32x4 acc[4][2];
#pragma unroll
    for (int i = 0; i < 4; i++)
#pragma unroll
        for (int j = 0; j < 2; j++) acc[i][j] = (f32x4){0.f, 0.f, 0.f, 0.f};

    auto stage = [&](int buf, int t) {
        char* sb = lds + buf * 16384;
        GLOAD_LDS16(gA + t * 32, sb + lAo);
        GLOAD_LDS16(gB + t * 32, sb + lBo);
    };

    stage(0, 0);
    stage(1, 1);

    int buf = 0;
    for (int t = 0; t < NT; ++t) {
        if (t < NT - 1)
            asm volatile("s_waitcnt vmcnt(2)\n\ts_barrier" ::: "memory");
        else
            asm volatile("s_waitcnt vmcnt(0)\n\ts_barrier" ::: "memory");
        if (t + 2 < NT) stage((buf + 2) % 3, t + 2);

        const char* pA = lds + buf * 16384;
        const char* pB = pA + 8192;
        bf16x8 af[4], bb[2];
#pragma unroll
        for (int m = 0; m < 4; m++) {
            int r = wr * 64 + m * 16 + l15;
            af[m] = *(const bf16x8*)(pA + r * 64 + ((g * 16) ^ (((r >> 1) & 3) << 4)));
        }
#pragma unroll
        for (int n = 0; n < 2; n++) {
            int r = wc * 32 + n * 16 + l15;
            bb[n] = *(const bf16x8*)(pB + r * 64 + ((g * 16) ^ (((r >> 1) & 3) << 4)));
        }
        __builtin_amdgcn_s_setprio(1);
#pragma unroll
        for (int m = 0; m < 4; m++)
#pragma unroll
            for (int n = 0; n < 2; n++)
                acc[m][n] = __builtin_amdgcn_mfma_f32_16x16x32_bf16(af[m], bb[n],
                                                                    acc[m][n], 0, 0, 0);
        __builtin_amdgcn_s_setprio(0);
        buf = (buf + 1) % 3;
    }

#pragma unroll
    for (int m = 0; m < 4; m++)
#pragma unroll
        for (int n = 0; n < 2; n++) {
            const int col = n0 + wc * 32 + n * 16 + l15;
            const float bv = bias[col];
#pragma unroll
            for (int rr = 0; rr < 4; rr++) {
                const int row = m0 + wr * 64 + m * 16 + g * 4 + rr;
                const long idx = (long)row * N + col;
                float val = acc[m][n][rr] + bv;
                if (EPI == 0) {
                    ((bf16_t*)Cv)[idx] = (bf16_t)val;
                } else if (EPI == 1) {
                    ((float*)Cv)[idx] = res[idx] + val;
                } else {
                    float ge = val / (1.f + __expf(-1.702f * val));
                    ((bf16_t*)Cv)[idx] = (bf16_t)ge;
                }
            }
        }
}

// ---------------- Flash attention v3: no-max softmax (unchanged) ----------------
__global__ __launch_bounds__(256) void attn_kernel(const bf16_t* __restrict__ Qd,
                                                   const bf16_t* __restrict__ Kd,
                                                   const bf16_t* __restrict__ Vt,
                                                   const int* __restrict__ cu,
                                                   int ncu,
                                                   bf16_t* __restrict__ out) {
    __shared__ bf16_t lK[64 * 104];
    __shared__ bf16_t lV[96 * 64];
    __shared__ bf16_t lP[4 * 16 * 72];

    const int tid = threadIdx.x;
    const int lane = tid & 63;
    const int l15 = lane & 15;
    const int g = lane >> 4;
    const int wid = tid >> 6;
    const int h = blockIdx.y;
    const int q0 = blockIdx.x * 64;

    int sseg = 0;
    for (int j = 1; j < ncu - 1; j++) if (q0 >= cu[j]) sseg = j;
    const int kbeg = cu[sseg], kend = cu[sseg + 1];

    bf16x8 aq[3];
    {
        const bf16_t* qp = Qd + ((long)h * NTOK + q0 + wid * 16 + l15) * 96;
#pragma unroll
        for (int ks = 0; ks < 3; ks++)
            aq[ks] = *(const bf16x8*)(qp + ks * 32 + g * 8);
    }

    for (int c = tid; c < 16 * 8; c += 256) {
        int d = 80 + c / 8, a = c % 8;
        bf16x8 v;
#pragma unroll
        for (int j = 0; j < 8; j++) v[j] = (d == 80) ? (bf16_t)1.f : (bf16_t)0.f;
        *(bf16x8*)((char*)lV + d * 128 + ((a * 16) ^ ((d & 7) << 4))) = v;
    }

    f32x4 o[6];
#pragma unroll
    for (int n = 0; n < 6; n++) o[n] = (f32x4){0.f, 0.f, 0.f, 0.f};

    bf16x8 rK[3], rV[3];
    auto ldK = [&](int kt) {
#pragma unroll
        for (int i = 0; i < 3; i++) {
            int c = tid + i * 256;
            int row = c / 12, c16 = c % 12;
            rK[i] = *(const bf16x8*)(Kd + ((long)h * NTOK + kt + row) * 96 + c16 * 8);
        }
    };
    auto ldV = [&](int kt) {
#pragma unroll
        for (int i = 0; i < 3; i++) {
            int c = tid + i * 256;
            if (c < 640) {
                int d = c / 8, a = c % 8;
                rV[i] = *(const bf16x8*)(Vt + ((long)h * HDIM + d) * NTOK + kt + a * 8);
            }
        }
    };
    auto wrKV = [&]() {
#pragma unroll
        for (int i = 0; i < 3; i++) {
            int c = tid + i * 256;
            int row = c / 12, c16 = c % 12;
            *(bf16x8*)(lK + row * 104 + c16 * 8) = rK[i];
        }
#pragma unroll
        for (int i = 0; i < 3; i++) {
            int c = tid + i * 256;
            if (c < 640) {
                int d = c / 8, a = c % 8;
                *(bf16x8*)((char*)lV + d * 128 + ((a * 16) ^ ((d & 7) << 4))) = rV[i];
            }
        }
    };

    ldK(kbeg); ldV(kbeg);
    wrKV();
    __syncthreads();

    for (int kt = kbeg; kt < kend; kt += 64) {
        const bool more = (kt + 64 < kend);
        if (more) { ldK(kt + 64); ldV(kt + 64); }

        f32x4 s[4];
#pragma unroll
        for (int n = 0; n < 4; n++) s[n] = (f32x4){0.f, 0.f, 0.f, 0.f};
#pragma unroll
        for (int n = 0; n < 4; n++)
#pragma unroll
            for (int ks = 0; ks < 3; ks++) {
                bf16x8 kf = *(const bf16x8*)(lK + (n * 16 + l15) * 104 + ks * 32 + g * 8);
                s[n] = __builtin_amdgcn_mfma_f32_16x16x32_bf16(aq[ks], kf, s[n], 0, 0, 0);
            }

#pragma unroll
        for (int n = 0; n < 4; n++)
#pragma unroll
            for (int r = 0; r < 4; r++)
                lP[wid * 1152 + (g * 4 + r) * 72 + n * 16 + l15] = (bf16_t)exp2f(s[n][r]);

        asm volatile("s_waitcnt lgkmcnt(0)" ::: "memory");
        bf16x8 pa[2];
#pragma unroll
        for (int ks = 0; ks < 2; ks++)
            pa[ks] = *(const bf16x8*)(lP + wid * 1152 + l15 * 72 + ks * 32 + g * 8);
#pragma unroll
        for (int n = 0; n < 6; n++)
#pragma unroll
            for (int ks = 0; ks < 2; ks++) {
                int rv = n * 16 + l15;
                bf16x8 vb = *(const bf16x8*)((char*)lV + rv * 128 +
                                             ((ks * 64 + g * 16) ^ ((rv & 7) << 4)));
                o[n] = __builtin_amdgcn_mfma_f32_16x16x32_bf16(pa[ks], vb, o[n], 0, 0, 0);
            }
        __syncthreads();
        if (more) wrKV();
        __syncthreads();
    }

    float lI[4];
#pragma unroll
    for (int r = 0; r < 4; r++) lI[r] = __shfl(o[5][r], lane & 48, 64);

#pragma unroll
    for (int n = 0; n < 5; n++)
#pragma unroll
        for (int r = 0; r < 4; r++) {
            int row = q0 + wid * 16 + g * 4 + r;
            out[(long)row * DIM + h * HDIM + n * 16 + l15] = (bf16_t)(o[n][r] / lI[r]);
        }
}

// ---------------- launch ----------------
extern "C" void kernel_launch(void* const* d_in, const int* in_sizes, int n_in,
                              void* d_out, int out_size, void* d_ws, size_t ws_size,
                              hipStream_t stream) {
    const float* hidden = (const float*)d_in[0];
    const float* rot    = (const float*)d_in[1];
    const int*   cu     = (const int*)d_in[2];
    const float* n1w    = (const float*)d_in[3];
    const float* n1b    = (const float*)d_in[4];
    const float* n2w    = (const float*)d_in[5];
    const float* n2b    = (const float*)d_in[6];
    const float* qkv_w  = (const float*)d_in[7];
    const float* qkv_b  = (const float*)d_in[8];
    const float* proj_w = (const float*)d_in[9];
    const float* proj_b = (const float*)d_in[10];
    const float* fc1_w  = (const float*)d_in[11];
    const float* fc1_b  = (const float*)d_in[12];
    const float* fc2_w  = (const float*)d_in[13];
    const float* fc2_b  = (const float*)d_in[14];
    float* outp = (float*)d_out;

    char* ws = (char*)d_ws;
    bf16_t* w2   = (bf16_t*)(ws);                  // [0,13.1M)        cvt->FC2
    bf16_t* w1   = (bf16_t*)(ws + 13107200);       // [13.1M,26.2M)    cvt->FC1
    bf16_t* wp   = (bf16_t*)(ws + 26214400);       // [26.2M,29.5M)    cvt->proj
    bf16_t* wq   = (bf16_t*)(ws + 29491200);       // [29.5M,39.3M)    cvt->QKV
    bf16_t* xln  = (bf16_t*)(ws + 39321600);       // [39.3M,49.8M)    LN1->QKV, LN2->FC1
    bf16_t* qkvb = (bf16_t*)(ws + 49807360);       // [49.8M,81.3M)    QKV->prep
    bf16_t* Qd   = (bf16_t*)(ws + 81264640);       // [81.3M,93.8M)    prep->attn
    bf16_t* Kd   = (bf16_t*)(ws + 93847552);       // [93.8M,106.4M)   prep->attn
    bf16_t* Vt   = (bf16_t*)(ws + 106430464);      // [106.4M,116.9M)  prep->attn
    bf16_t* attno= (bf16_t*)(ws + 116916224);      // [116.9M,127.4M)  attn->proj
    bf16_t* act  = (bf16_t*)(ws + 49807360);       // [49.8M,91.75M)   FC1->FC2 (qkvb/Qd dead)
    // h (f32) lives in d_out: proj writes (EPI1), LN2 reads, FC2 (EPI1) accumulates.

    int ncu = in_sizes[2];

    cvt_all<<<2048, 256, 0, stream>>>(fc2_w, fc1_w, proj_w, qkv_w,
                                      w2, w1, wp, wq,
                                      DIM * MLP, MLP * DIM, DIM * DIM, QKV_N * DIM);

    ln_kernel<<<NTOK, 256, 0, stream>>>(hidden, n1w, n1b, xln);
    // QKV: 4096x3840x1280 -> 15x32 = 480 blocks (BN=256), NT=40
    gemmU<0><<<dim3(QKV_N / 256, NTOK / 128, 1), 512, 0, stream>>>(
        xln, wq, qkv_b, qkvb, NTOK, QKV_N, DIM);
    prep_kernel<<<dim3(NTOK / 64, NHEADS), 256, 0, stream>>>(qkvb, rot, Qd, Kd, Vt);
    attn_kernel<<<dim3(NTOK / 64, NHEADS), 256, 0, stream>>>(Qd, Kd, Vt, cu, ncu, attno);
    // proj: 4096x1280x1280 -> 10x32 = 320 blocks, NT=40, direct h = hidden+acc+bias
    gemmS<1><<<dim3(DIM / 128, NTOK / 128, 1), 512, 0, stream>>>(
        attno, wp, proj_b, hidden, outp, NTOK, DIM, DIM, DIM);
    ln_kernel<<<NTOK, 256, 0, stream>>>(outp, n2w, n2b, xln);
    // FC1: 4096x5120x1280 -> 20x32 = 640 blocks (BN=256), NT=40
    gemmU<2><<<dim3(MLP / 256, NTOK / 128, 1), 512, 0, stream>>>(
        xln, w1, fc1_b, act, NTOK, MLP, DIM);
    // FC2: 4096x1280x5120 -> 10x32 = 320 blocks, NT=160, direct out = h+acc+bias
    gemmS<1><<<dim3(DIM / 128, NTOK / 128, 1), 512, 0, stream>>>(
        act, w2, fc2_b, outp, outp, NTOK, DIM, MLP, MLP);
}